// Round 1
// baseline (1276.858 us; speedup 1.0000x reference)
//
#include <hip/hip_runtime.h>

// ---------------- kernels ----------------

__global__ void k_deg(const int* __restrict__ dst, float* __restrict__ deg, int E) {
    int i = blockIdx.x * blockDim.x + threadIdx.x;
    if (i < E) atomicAdd(&deg[dst[i]], 1.0f);
}

__global__ void k_dinv(float* __restrict__ deg, int n) {
    int i = blockIdx.x * blockDim.x + threadIdx.x;
    if (i < n) deg[i] = rsqrtf(deg[i] + 1.0f);   // self-loop: deg includes +1
}

// layer-1 aggregation on raw x (aggregate-then-project: only 2 floats/edge)
__global__ void k_agg1(const int* __restrict__ src, const int* __restrict__ dst,
                       const float* __restrict__ dinv, const float* __restrict__ x,
                       float* __restrict__ agg1, int E) {
    int i = blockIdx.x * blockDim.x + threadIdx.x;
    if (i >= E) return;
    int s = src[i], d = dst[i];
    float w = dinv[s] * dinv[d];
    float2 xs = *reinterpret_cast<const float2*>(&x[2 * s]);
    atomicAdd(&agg1[2 * d],     w * xs.x);
    atomicAdd(&agg1[2 * d + 1], w * xs.y);
}

// per-node: h1 = relu((agg1 + dinv^2 * x) @ W1 + b1); z = h1 @ W2   (3 floats out)
__global__ void k_z(const float* __restrict__ agg1, const float* __restrict__ x,
                    const float* __restrict__ dinv,
                    const float* __restrict__ W1, const float* __restrict__ b1,
                    const float* __restrict__ W2, float* __restrict__ z, int n) {
    __shared__ float sW1[128], sb1[64], sW2[192];
    for (int t = threadIdx.x; t < 128; t += blockDim.x) sW1[t] = W1[t];
    for (int t = threadIdx.x; t < 64;  t += blockDim.x) sb1[t] = b1[t];
    for (int t = threadIdx.x; t < 192; t += blockDim.x) sW2[t] = W2[t];
    __syncthreads();
    int i = blockIdx.x * blockDim.x + threadIdx.x;
    if (i >= n) return;
    float di = dinv[i], w = di * di;
    float2 xs = *reinterpret_cast<const float2*>(&x[2 * i]);
    float a0 = agg1[2 * i]     + w * xs.x;   // add self-loop contribution
    float a1 = agg1[2 * i + 1] + w * xs.y;
    float z0 = 0.f, z1 = 0.f, z2 = 0.f;
#pragma unroll
    for (int j = 0; j < 64; ++j) {
        float h = fmaf(a0, sW1[j], fmaf(a1, sW1[64 + j], sb1[j]));  // W1[0][j],W1[1][j]
        h = fmaxf(h, 0.f);
        z0 = fmaf(h, sW2[3 * j],     z0);
        z1 = fmaf(h, sW2[3 * j + 1], z1);
        z2 = fmaf(h, sW2[3 * j + 2], z2);
    }
    z[3 * i] = z0; z[3 * i + 1] = z1; z[3 * i + 2] = z2;
}

// layer-2 aggregation on z (project-then-aggregate: only 3 floats/edge)
__global__ void k_agg2(const int* __restrict__ src, const int* __restrict__ dst,
                       const float* __restrict__ dinv, const float* __restrict__ z,
                       float* __restrict__ agg2, int E) {
    int i = blockIdx.x * blockDim.x + threadIdx.x;
    if (i >= E) return;
    int s = src[i], d = dst[i];
    float w = dinv[s] * dinv[d];
    atomicAdd(&agg2[3 * d],     w * z[3 * s]);
    atomicAdd(&agg2[3 * d + 1], w * z[3 * s + 1]);
    atomicAdd(&agg2[3 * d + 2], w * z[3 * s + 2]);
}

// per-node epilogue: out_i = agg2 + dinv^2*z + b2; pool into per-graph sums
__global__ void k_pool(const float* __restrict__ agg2, const float* __restrict__ z,
                       const float* __restrict__ dinv, const float* __restrict__ b2,
                       const int* __restrict__ batch,
                       float* __restrict__ pooled, float* __restrict__ cnt, int n) {
    int i = blockIdx.x * blockDim.x + threadIdx.x;
    if (i >= n) return;
    float di = dinv[i], w = di * di;
    float o0 = agg2[3 * i]     + w * z[3 * i]     + b2[0];
    float o1 = agg2[3 * i + 1] + w * z[3 * i + 1] + b2[1];
    float o2 = agg2[3 * i + 2] + w * z[3 * i + 2] + b2[2];
    int g = batch[i];
    atomicAdd(&pooled[3 * g],     o0);
    atomicAdd(&pooled[3 * g + 1], o1);
    atomicAdd(&pooled[3 * g + 2], o2);
    atomicAdd(&cnt[g], 1.0f);
}

__global__ void k_out(const float* __restrict__ pooled, const float* __restrict__ cnt,
                      float* __restrict__ out, int G) {
    int g = blockIdx.x * blockDim.x + threadIdx.x;
    if (g >= G) return;
    float c = fmaxf(cnt[g], 1.0f);
    float p0 = pooled[3 * g] / c, p1 = pooled[3 * g + 1] / c, p2 = pooled[3 * g + 2] / c;
    float m = fmaxf(p0, fmaxf(p1, p2));
    float s = expf(p0 - m) + expf(p1 - m) + expf(p2 - m);
    float l = logf(s);
    out[3 * g] = p0 - m - l;
    out[3 * g + 1] = p1 - m - l;
    out[3 * g + 2] = p2 - m - l;
}

// ---------------- launch ----------------

extern "C" void kernel_launch(void* const* d_in, const int* in_sizes, int n_in,
                              void* d_out, int out_size, void* d_ws, size_t ws_size,
                              hipStream_t stream) {
    const float* x     = (const float*)d_in[0];
    const int*   ei    = (const int*)  d_in[1];
    const int*   batch = (const int*)  d_in[2];
    const float* W1    = (const float*)d_in[3];
    const float* b1    = (const float*)d_in[4];
    const float* W2    = (const float*)d_in[5];
    const float* b2    = (const float*)d_in[6];
    float*       out   = (float*)d_out;

    const int n = in_sizes[2];          // 200000
    const int E = in_sizes[1] / 2;      // 3200000
    const int G = out_size / 3;         // 512
    const int* src = ei;                // edge_index[0]
    const int* dst = ei + E;            // edge_index[1]

    float* ws     = (float*)d_ws;
    float* deg    = ws;                 // n   (becomes dinv in place)
    float* agg1   = deg + n;            // 2n
    float* agg2   = agg1 + 2 * (size_t)n;   // 3n
    float* pooled = agg2 + 3 * (size_t)n;   // 3G
    float* cnt    = pooled + 3 * (size_t)G; // G
    float* z      = cnt + G;            // 3n (no zeroing needed)

    // zero all accumulators (contiguous region) every call — capture-safe
    size_t zero_floats = (size_t)6 * n + (size_t)4 * G;
    hipMemsetAsync(ws, 0, zero_floats * sizeof(float), stream);

    const int B = 256;
    k_deg <<<(E + B - 1) / B, B, 0, stream>>>(dst, deg, E);
    k_dinv<<<(n + B - 1) / B, B, 0, stream>>>(deg, n);
    k_agg1<<<(E + B - 1) / B, B, 0, stream>>>(src, dst, deg, x, agg1, E);
    k_z   <<<(n + B - 1) / B, B, 0, stream>>>(agg1, x, deg, W1, b1, W2, z, n);
    k_agg2<<<(E + B - 1) / B, B, 0, stream>>>(src, dst, deg, z, agg2, E);
    k_pool<<<(n + B - 1) / B, B, 0, stream>>>(agg2, z, deg, b2, batch, pooled, cnt, n);
    k_out <<<(G + B - 1) / B, B, 0, stream>>>(pooled, cnt, out, G);
}

// Round 2
// 343.827 us; speedup vs baseline: 3.7137x; 3.7137x over previous
//
#include <hip/hip_runtime.h>

// ============ PATH A: CSR-gather (atomic-light) ============

__global__ void kA_hist(const int* __restrict__ dst, int* __restrict__ hist,
                        int* __restrict__ rank, int E) {
    int i = blockIdx.x * blockDim.x + threadIdx.x;
    if (i < E) rank[i] = atomicAdd(&hist[dst[i]], 1);
}

// per-256-block exclusive scan of hist -> rs_part, block sums -> bsum; also dinv
__global__ void kA_scanA(const int* __restrict__ hist, int* __restrict__ rs_part,
                         int* __restrict__ bsum, float* __restrict__ dinv, int n) {
    __shared__ int s[256];
    int t = threadIdx.x, i = blockIdx.x * 256 + t;
    int h = (i < n) ? hist[i] : 0;
    s[t] = h; __syncthreads();
    for (int off = 1; off < 256; off <<= 1) {
        int v = (t >= off) ? s[t - off] : 0;
        __syncthreads();
        s[t] += v;
        __syncthreads();
    }
    if (i < n) { rs_part[i] = s[t] - h; dinv[i] = rsqrtf((float)h + 1.0f); }
    if (t == 255) bsum[blockIdx.x] = s[255];
}

// single block: exclusive scan of <=1024 block sums
__global__ void kA_scanB(const int* __restrict__ bsum, int* __restrict__ bsum_ex, int NB) {
    __shared__ int s[1024];
    int t = threadIdx.x;
    int v = (t < NB) ? bsum[t] : 0;
    s[t] = v; __syncthreads();
    for (int off = 1; off < 1024; off <<= 1) {
        int u = (t >= off) ? s[t - off] : 0;
        __syncthreads();
        s[t] += u;
        __syncthreads();
    }
    if (t < NB) bsum_ex[t] = s[t] - v;
}

// atomic-free CSR fill: slot = global_excl_scan(dst) + rank
__global__ void kA_fill(const int* __restrict__ src, const int* __restrict__ dst,
                        const int* __restrict__ rank, const int* __restrict__ rs_part,
                        const int* __restrict__ bsum_ex, int* __restrict__ csr, int E) {
    int i = blockIdx.x * blockDim.x + threadIdx.x;
    if (i >= E) return;
    int d = dst[i];
    csr[rs_part[d] + bsum_ex[d >> 8] + rank[i]] = src[i];
}

// gather layer-1 agg on raw x (2 floats) + fused MLP -> z (3 floats)
__global__ void kA_gz(const int* __restrict__ csr, const int* __restrict__ rs_part,
                      const int* __restrict__ bsum_ex, const int* __restrict__ hist,
                      const float* __restrict__ dinv, const float* __restrict__ x,
                      const float* __restrict__ W1, const float* __restrict__ b1,
                      const float* __restrict__ W2, float* __restrict__ z, int n) {
    __shared__ float sW1[128], sb1[64], sW2[192];
    for (int t = threadIdx.x; t < 128; t += blockDim.x) sW1[t] = W1[t];
    for (int t = threadIdx.x; t < 64;  t += blockDim.x) sb1[t] = b1[t];
    for (int t = threadIdx.x; t < 192; t += blockDim.x) sW2[t] = W2[t];
    __syncthreads();
    int i = blockIdx.x * blockDim.x + threadIdx.x;
    if (i >= n) return;
    float di = dinv[i];
    float2 xs = *reinterpret_cast<const float2*>(&x[2 * i]);
    float acc0 = di * xs.x, acc1 = di * xs.y;          // self-loop term (x di later)
    int start = rs_part[i] + bsum_ex[i >> 8], c = hist[i];
    for (int e = 0; e < c; ++e) {
        int s = csr[start + e];
        float ds = dinv[s];
        float2 v = *reinterpret_cast<const float2*>(&x[2 * s]);
        acc0 = fmaf(ds, v.x, acc0);
        acc1 = fmaf(ds, v.y, acc1);
    }
    float a0 = di * acc0, a1 = di * acc1;
    float z0 = 0.f, z1 = 0.f, z2 = 0.f;
#pragma unroll
    for (int j = 0; j < 64; ++j) {
        float h = fmaf(a0, sW1[j], fmaf(a1, sW1[64 + j], sb1[j]));
        h = fmaxf(h, 0.f);
        z0 = fmaf(h, sW2[3 * j],     z0);
        z1 = fmaf(h, sW2[3 * j + 1], z1);
        z2 = fmaf(h, sW2[3 * j + 2], z2);
    }
    z[3 * i] = z0; z[3 * i + 1] = z1; z[3 * i + 2] = z2;
}

// gather layer-2 agg on z + bias + wave-reduced pooling
__global__ void kA_g2(const int* __restrict__ csr, const int* __restrict__ rs_part,
                      const int* __restrict__ bsum_ex, const int* __restrict__ hist,
                      const float* __restrict__ dinv, const float* __restrict__ zv,
                      const float* __restrict__ b2, const int* __restrict__ batch,
                      float* __restrict__ pooled, float* __restrict__ cnt, int n) {
    int i = blockIdx.x * blockDim.x + threadIdx.x;
    float o0 = 0.f, o1 = 0.f, o2 = 0.f, vc = 0.f;
    int g = -1;
    if (i < n) {
        float di = dinv[i];
        float a0 = di * zv[3 * i], a1 = di * zv[3 * i + 1], a2 = di * zv[3 * i + 2];
        int start = rs_part[i] + bsum_ex[i >> 8], c = hist[i];
        for (int e = 0; e < c; ++e) {
            int s = csr[start + e];
            float ds = dinv[s];
            a0 = fmaf(ds, zv[3 * s],     a0);
            a1 = fmaf(ds, zv[3 * s + 1], a1);
            a2 = fmaf(ds, zv[3 * s + 2], a2);
        }
        o0 = fmaf(di, a0, b2[0]);
        o1 = fmaf(di, a1, b2[1]);
        o2 = fmaf(di, a2, b2[2]);
        vc = 1.f;
        g = batch[i];
    }
    // batch is sorted: most waves are single-graph -> 1 set of atomics per wave
    int g0 = __shfl(g, 0);
    bool uni = __all(g == g0);
    if (uni) {
        for (int off = 32; off; off >>= 1) {
            o0 += __shfl_down(o0, off);
            o1 += __shfl_down(o1, off);
            o2 += __shfl_down(o2, off);
            vc += __shfl_down(vc, off);
        }
        if ((threadIdx.x & 63) == 0 && g0 >= 0) {
            atomicAdd(&pooled[3 * g0],     o0);
            atomicAdd(&pooled[3 * g0 + 1], o1);
            atomicAdd(&pooled[3 * g0 + 2], o2);
            atomicAdd(&cnt[g0], vc);
        }
    } else if (g >= 0) {
        atomicAdd(&pooled[3 * g],     o0);
        atomicAdd(&pooled[3 * g + 1], o1);
        atomicAdd(&pooled[3 * g + 2], o2);
        atomicAdd(&cnt[g], 1.f);
    }
}

__global__ void k_out(const float* __restrict__ pooled, const float* __restrict__ cnt,
                      float* __restrict__ out, int G) {
    int g = blockIdx.x * blockDim.x + threadIdx.x;
    if (g >= G) return;
    float c = fmaxf(cnt[g], 1.0f);
    float p0 = pooled[3 * g] / c, p1 = pooled[3 * g + 1] / c, p2 = pooled[3 * g + 2] / c;
    float m = fmaxf(p0, fmaxf(p1, p2));
    float s = expf(p0 - m) + expf(p1 - m) + expf(p2 - m);
    float l = logf(s);
    out[3 * g]     = p0 - m - l;
    out[3 * g + 1] = p1 - m - l;
    out[3 * g + 2] = p2 - m - l;
}

// ============ PATH B: fallback (round-1 atomic scatter) ============

__global__ void kB_deg(const int* __restrict__ dst, float* __restrict__ deg, int E) {
    int i = blockIdx.x * blockDim.x + threadIdx.x;
    if (i < E) atomicAdd(&deg[dst[i]], 1.0f);
}

__global__ void kB_dinv(float* __restrict__ deg, int n) {
    int i = blockIdx.x * blockDim.x + threadIdx.x;
    if (i < n) deg[i] = rsqrtf(deg[i] + 1.0f);
}

__global__ void kB_agg1(const int* __restrict__ src, const int* __restrict__ dst,
                        const float* __restrict__ dinv, const float* __restrict__ x,
                        float* __restrict__ agg1, int E) {
    int i = blockIdx.x * blockDim.x + threadIdx.x;
    if (i >= E) return;
    int s = src[i], d = dst[i];
    float w = dinv[s] * dinv[d];
    float2 xs = *reinterpret_cast<const float2*>(&x[2 * s]);
    atomicAdd(&agg1[2 * d],     w * xs.x);
    atomicAdd(&agg1[2 * d + 1], w * xs.y);
}

__global__ void kB_z(const float* __restrict__ agg1, const float* __restrict__ x,
                     const float* __restrict__ dinv,
                     const float* __restrict__ W1, const float* __restrict__ b1,
                     const float* __restrict__ W2, float* __restrict__ z, int n) {
    __shared__ float sW1[128], sb1[64], sW2[192];
    for (int t = threadIdx.x; t < 128; t += blockDim.x) sW1[t] = W1[t];
    for (int t = threadIdx.x; t < 64;  t += blockDim.x) sb1[t] = b1[t];
    for (int t = threadIdx.x; t < 192; t += blockDim.x) sW2[t] = W2[t];
    __syncthreads();
    int i = blockIdx.x * blockDim.x + threadIdx.x;
    if (i >= n) return;
    float di = dinv[i], w = di * di;
    float2 xs = *reinterpret_cast<const float2*>(&x[2 * i]);
    float a0 = agg1[2 * i]     + w * xs.x;
    float a1 = agg1[2 * i + 1] + w * xs.y;
    float z0 = 0.f, z1 = 0.f, z2 = 0.f;
#pragma unroll
    for (int j = 0; j < 64; ++j) {
        float h = fmaf(a0, sW1[j], fmaf(a1, sW1[64 + j], sb1[j]));
        h = fmaxf(h, 0.f);
        z0 = fmaf(h, sW2[3 * j],     z0);
        z1 = fmaf(h, sW2[3 * j + 1], z1);
        z2 = fmaf(h, sW2[3 * j + 2], z2);
    }
    z[3 * i] = z0; z[3 * i + 1] = z1; z[3 * i + 2] = z2;
}

__global__ void kB_agg2(const int* __restrict__ src, const int* __restrict__ dst,
                        const float* __restrict__ dinv, const float* __restrict__ z,
                        float* __restrict__ agg2, int E) {
    int i = blockIdx.x * blockDim.x + threadIdx.x;
    if (i >= E) return;
    int s = src[i], d = dst[i];
    float w = dinv[s] * dinv[d];
    atomicAdd(&agg2[3 * d],     w * z[3 * s]);
    atomicAdd(&agg2[3 * d + 1], w * z[3 * s + 1]);
    atomicAdd(&agg2[3 * d + 2], w * z[3 * s + 2]);
}

__global__ void kB_pool(const float* __restrict__ agg2, const float* __restrict__ z,
                        const float* __restrict__ dinv, const float* __restrict__ b2,
                        const int* __restrict__ batch,
                        float* __restrict__ pooled, float* __restrict__ cnt, int n) {
    int i = blockIdx.x * blockDim.x + threadIdx.x;
    if (i >= n) return;
    float di = dinv[i], w = di * di;
    float o0 = agg2[3 * i]     + w * z[3 * i]     + b2[0];
    float o1 = agg2[3 * i + 1] + w * z[3 * i + 1] + b2[1];
    float o2 = agg2[3 * i + 2] + w * z[3 * i + 2] + b2[2];
    int g = batch[i];
    atomicAdd(&pooled[3 * g],     o0);
    atomicAdd(&pooled[3 * g + 1], o1);
    atomicAdd(&pooled[3 * g + 2], o2);
    atomicAdd(&cnt[g], 1.0f);
}

// ============ launch ============

extern "C" void kernel_launch(void* const* d_in, const int* in_sizes, int n_in,
                              void* d_out, int out_size, void* d_ws, size_t ws_size,
                              hipStream_t stream) {
    const float* x     = (const float*)d_in[0];
    const int*   ei    = (const int*)  d_in[1];
    const int*   batch = (const int*)  d_in[2];
    const float* W1    = (const float*)d_in[3];
    const float* b1    = (const float*)d_in[4];
    const float* W2    = (const float*)d_in[5];
    const float* b2    = (const float*)d_in[6];
    float*       out   = (float*)d_out;

    const int n = in_sizes[2];
    const int E = in_sizes[1] / 2;
    const int G = out_size / 3;
    const int* src = ei;
    const int* dst = ei + E;
    const int B = 256;
    const int NB = (n + 255) / 256;   // scan blocks

    // Path-A workspace layout (4B units)
    size_t o = 0;
    size_t off_hist = o; o += n;
    size_t off_pool = o; o += (size_t)3 * G;
    size_t off_cnt  = o; o += G;           // [0, o) zeroed
    size_t zeroA = o;
    size_t off_rank = o; o += E;
    size_t off_csr  = o; o += E;
    size_t off_rsp  = o; o += n;
    size_t off_bs   = o; o += 1024;
    size_t off_bse  = o; o += 1024;
    size_t off_dinv = o; o += n;
    size_t off_z    = o; o += (size_t)3 * n;
    size_t needA = o * 4;

    if (ws_size >= needA && NB <= 1024) {
        int*   hist    = (int*)d_ws + off_hist;
        float* pooled  = (float*)d_ws + off_pool;
        float* cnt     = (float*)d_ws + off_cnt;
        int*   rank    = (int*)d_ws + off_rank;
        int*   csr     = (int*)d_ws + off_csr;
        int*   rs_part = (int*)d_ws + off_rsp;
        int*   bsum    = (int*)d_ws + off_bs;
        int*   bsum_ex = (int*)d_ws + off_bse;
        float* dinv    = (float*)d_ws + off_dinv;
        float* z       = (float*)d_ws + off_z;

        hipMemsetAsync(d_ws, 0, zeroA * 4, stream);
        kA_hist <<<(E + B - 1) / B, B, 0, stream>>>(dst, hist, rank, E);
        kA_scanA<<<NB, 256, 0, stream>>>(hist, rs_part, bsum, dinv, n);
        kA_scanB<<<1, 1024, 0, stream>>>(bsum, bsum_ex, NB);
        kA_fill <<<(E + B - 1) / B, B, 0, stream>>>(src, dst, rank, rs_part, bsum_ex, csr, E);
        kA_gz   <<<(n + B - 1) / B, B, 0, stream>>>(csr, rs_part, bsum_ex, hist, dinv, x,
                                                    W1, b1, W2, z, n);
        kA_g2   <<<(n + B - 1) / B, B, 0, stream>>>(csr, rs_part, bsum_ex, hist, dinv, z,
                                                    b2, batch, pooled, cnt, n);
        k_out   <<<(G + B - 1) / B, B, 0, stream>>>(pooled, cnt, out, G);
    } else {
        // fallback: round-1 scatter path (needs (6n+4G)*4 bytes)
        float* ws     = (float*)d_ws;
        float* deg    = ws;
        float* agg1   = deg + n;
        float* agg2   = agg1 + 2 * (size_t)n;
        float* pooled = agg2 + 3 * (size_t)n;
        float* cnt    = pooled + 3 * (size_t)G;
        float* z      = cnt + G;

        size_t zero_floats = (size_t)6 * n + (size_t)4 * G;
        hipMemsetAsync(ws, 0, zero_floats * sizeof(float), stream);
        kB_deg <<<(E + B - 1) / B, B, 0, stream>>>(dst, deg, E);
        kB_dinv<<<(n + B - 1) / B, B, 0, stream>>>(deg, n);
        kB_agg1<<<(E + B - 1) / B, B, 0, stream>>>(src, dst, deg, x, agg1, E);
        kB_z   <<<(n + B - 1) / B, B, 0, stream>>>(agg1, x, deg, W1, b1, W2, z, n);
        kB_agg2<<<(E + B - 1) / B, B, 0, stream>>>(src, dst, deg, z, agg2, E);
        kB_pool<<<(n + B - 1) / B, B, 0, stream>>>(agg2, z, deg, b2, batch, pooled, cnt, n);
        k_out  <<<(G + B - 1) / B, B, 0, stream>>>(pooled, cnt, out, G);
    }
}

// Round 3
// 288.722 us; speedup vs baseline: 4.4225x; 1.1909x over previous
//
#include <hip/hip_runtime.h>

#define NBLK 512          // partition blocks
#define SH   9
#define BUCK 512          // nodes per bucket = 1<<SH
#define NBUK_MAX 512

// ============ PATH A: bucket counting-sort + LDS accumulation ============

// Pass A: per-block LDS histogram of dst buckets -> hist2d[bucket*NBLK + block]
__global__ void k_pcount(const int* __restrict__ dst, int* __restrict__ hist2d,
                         int E, int nbuk, int chunk) {
    __shared__ int h[NBUK_MAX];
    for (int t = threadIdx.x; t < nbuk; t += 256) h[t] = 0;
    __syncthreads();
    int beg = blockIdx.x * chunk, end = min(beg + chunk, E);
    for (int i = beg + threadIdx.x; i < end; i += 256)
        atomicAdd(&h[dst[i] >> SH], 1);
    __syncthreads();
    for (int t = threadIdx.x; t < nbuk; t += 256)
        hist2d[t * NBLK + blockIdx.x] = h[t];
}

// generic 256-block exclusive scan -> partials + block sums
__global__ void k_scanA(const int* __restrict__ in, int* __restrict__ outp,
                        int* __restrict__ bsum, int M) {
    __shared__ int s[256];
    int t = threadIdx.x, i = blockIdx.x * 256 + t;
    int h = (i < M) ? in[i] : 0;
    s[t] = h; __syncthreads();
    for (int off = 1; off < 256; off <<= 1) {
        int v = (t >= off) ? s[t - off] : 0;
        __syncthreads();
        s[t] += v;
        __syncthreads();
    }
    if (i < M) outp[i] = s[t] - h;
    if (t == 255) bsum[blockIdx.x] = s[255];
}

__global__ void k_scanB(const int* __restrict__ bsum, int* __restrict__ bsum_ex, int NB) {
    __shared__ int s[1024];
    int t = threadIdx.x;
    int v = (t < NB) ? bsum[t] : 0;
    s[t] = v; __syncthreads();
    for (int off = 1; off < 1024; off <<= 1) {
        int u = (t >= off) ? s[t - off] : 0;
        __syncthreads();
        s[t] += u;
        __syncthreads();
    }
    if (t < NB) bsum_ex[t] = s[t] - v;
}

__device__ __forceinline__ int scan_off(const int* rs2, const int* bse, int j) {
    return rs2[j] + bse[j >> 8];
}

// Pass B: LDS cursors, write packed (src<<SH | dst_low) in bucket-partitioned order
__global__ void k_pfill(const int* __restrict__ src, const int* __restrict__ dst,
                        const int* __restrict__ rs2, const int* __restrict__ bse,
                        int* __restrict__ part, int E, int nbuk, int chunk) {
    __shared__ int cur[NBUK_MAX];
    for (int t = threadIdx.x; t < nbuk; t += 256) {
        int j = t * NBLK + blockIdx.x;
        cur[t] = scan_off(rs2, bse, j);
    }
    __syncthreads();
    int beg = blockIdx.x * chunk, end = min(beg + chunk, E);
    for (int i = beg + threadIdx.x; i < end; i += 256) {
        int d = dst[i];
        int pos = atomicAdd(&cur[d >> SH], 1);     // LDS atomic
        part[pos] = (src[i] << SH) | (d & (BUCK - 1));
    }
}

// per-bucket degree -> dinv (fused)
__global__ void k_bdeg(const int* __restrict__ part, const int* __restrict__ rs2,
                       const int* __restrict__ bse, float* __restrict__ dinv,
                       int n, int nbuk, int E) {
    __shared__ int c[BUCK];
    int b = blockIdx.x;
    for (int t = threadIdx.x; t < BUCK; t += 256) c[t] = 0;
    __syncthreads();
    int beg = scan_off(rs2, bse, b * NBLK);
    int end = (b + 1 < nbuk) ? scan_off(rs2, bse, (b + 1) * NBLK) : E;
    for (int i = beg + threadIdx.x; i < end; i += 256)
        atomicAdd(&c[part[i] & (BUCK - 1)], 1);
    __syncthreads();
    int base = b << SH;
    for (int t = threadIdx.x; t < BUCK; t += 256) {
        int node = base + t;
        if (node < n) dinv[node] = rsqrtf((float)c[t] + 1.0f);
    }
}

// layer-1 bucket aggregation on x (LDS bins) + fused MLP -> z (float4)
__global__ void k_bz(const int* __restrict__ part, const int* __restrict__ rs2,
                     const int* __restrict__ bse, const float* __restrict__ dinv,
                     const float* __restrict__ x,
                     const float* __restrict__ W1, const float* __restrict__ b1,
                     const float* __restrict__ W2, float4* __restrict__ z,
                     int n, int nbuk, int E) {
    __shared__ float ax[BUCK], ay[BUCK];
    __shared__ float sW1[128], sb1[64], sW2[192];
    for (int t = threadIdx.x; t < 128; t += 256) sW1[t] = W1[t];
    for (int t = threadIdx.x; t < 64;  t += 256) sb1[t] = b1[t];
    for (int t = threadIdx.x; t < 192; t += 256) sW2[t] = W2[t];
    for (int t = threadIdx.x; t < BUCK; t += 256) { ax[t] = 0.f; ay[t] = 0.f; }
    __syncthreads();
    int b = blockIdx.x;
    int beg = scan_off(rs2, bse, b * NBLK);
    int end = (b + 1 < nbuk) ? scan_off(rs2, bse, (b + 1) * NBLK) : E;
    for (int i = beg + threadIdx.x; i < end; i += 256) {
        int e = part[i];
        int s = e >> SH, dl = e & (BUCK - 1);
        float w = dinv[s];
        float2 xs = *reinterpret_cast<const float2*>(&x[2 * s]);
        atomicAdd(&ax[dl], w * xs.x);
        atomicAdd(&ay[dl], w * xs.y);
    }
    __syncthreads();
    int base = b << SH;
    for (int t = threadIdx.x; t < BUCK; t += 256) {
        int node = base + t;
        if (node >= n) continue;
        float di = dinv[node];
        float2 xs = *reinterpret_cast<const float2*>(&x[2 * node]);
        float a0 = di * (ax[t] + di * xs.x);
        float a1 = di * (ay[t] + di * xs.y);
        float z0 = 0.f, z1 = 0.f, z2 = 0.f;
#pragma unroll
        for (int jj = 0; jj < 64; ++jj) {
            float h = fmaf(a0, sW1[jj], fmaf(a1, sW1[64 + jj], sb1[jj]));
            h = fmaxf(h, 0.f);
            z0 = fmaf(h, sW2[3 * jj],     z0);
            z1 = fmaf(h, sW2[3 * jj + 1], z1);
            z2 = fmaf(h, sW2[3 * jj + 2], z2);
        }
        z[node] = make_float4(z0, z1, z2, 0.f);
    }
}

// layer-2 bucket aggregation on z + epilogue + sorted-batch wave pooling
__global__ void k_bout(const int* __restrict__ part, const int* __restrict__ rs2,
                       const int* __restrict__ bse, const float* __restrict__ dinv,
                       const float4* __restrict__ z, const float* __restrict__ b2,
                       const int* __restrict__ batch,
                       float* __restrict__ pooled, float* __restrict__ cnt,
                       int n, int nbuk, int E) {
    __shared__ float a0s[BUCK], a1s[BUCK], a2s[BUCK];
    for (int t = threadIdx.x; t < BUCK; t += 256) { a0s[t] = 0.f; a1s[t] = 0.f; a2s[t] = 0.f; }
    __syncthreads();
    int b = blockIdx.x;
    int beg = scan_off(rs2, bse, b * NBLK);
    int end = (b + 1 < nbuk) ? scan_off(rs2, bse, (b + 1) * NBLK) : E;
    for (int i = beg + threadIdx.x; i < end; i += 256) {
        int e = part[i];
        int s = e >> SH, dl = e & (BUCK - 1);
        float w = dinv[s];
        float4 zs = z[s];
        atomicAdd(&a0s[dl], w * zs.x);
        atomicAdd(&a1s[dl], w * zs.y);
        atomicAdd(&a2s[dl], w * zs.z);
    }
    __syncthreads();
    float bb0 = b2[0], bb1 = b2[1], bb2 = b2[2];
    int base = b << SH;
    for (int t = threadIdx.x; t < BUCK; t += 256) {
        int node = base + t;
        float o0 = 0.f, o1 = 0.f, o2 = 0.f, vc = 0.f;
        int g = -1;
        if (node < n) {
            float di = dinv[node];
            float4 zs = z[node];
            o0 = fmaf(di, a0s[t] + di * zs.x, bb0);
            o1 = fmaf(di, a1s[t] + di * zs.y, bb1);
            o2 = fmaf(di, a2s[t] + di * zs.z, bb2);
            vc = 1.f;
            g = batch[node];
        }
        int g0 = __shfl(g, 0);
        bool uni = __all(g == g0);
        if (uni) {
            for (int off = 32; off; off >>= 1) {
                o0 += __shfl_down(o0, off);
                o1 += __shfl_down(o1, off);
                o2 += __shfl_down(o2, off);
                vc += __shfl_down(vc, off);
            }
            if ((threadIdx.x & 63) == 0 && g0 >= 0) {
                atomicAdd(&pooled[3 * g0],     o0);
                atomicAdd(&pooled[3 * g0 + 1], o1);
                atomicAdd(&pooled[3 * g0 + 2], o2);
                atomicAdd(&cnt[g0], vc);
            }
        } else if (g >= 0) {
            atomicAdd(&pooled[3 * g],     o0);
            atomicAdd(&pooled[3 * g + 1], o1);
            atomicAdd(&pooled[3 * g + 2], o2);
            atomicAdd(&cnt[g], 1.f);
        }
    }
}

__global__ void k_out(const float* __restrict__ pooled, const float* __restrict__ cnt,
                      float* __restrict__ out, int G) {
    int g = blockIdx.x * blockDim.x + threadIdx.x;
    if (g >= G) return;
    float c = fmaxf(cnt[g], 1.0f);
    float p0 = pooled[3 * g] / c, p1 = pooled[3 * g + 1] / c, p2 = pooled[3 * g + 2] / c;
    float m = fmaxf(p0, fmaxf(p1, p2));
    float s = expf(p0 - m) + expf(p1 - m) + expf(p2 - m);
    float l = logf(s);
    out[3 * g]     = p0 - m - l;
    out[3 * g + 1] = p1 - m - l;
    out[3 * g + 2] = p2 - m - l;
}

// ============ PATH B: fallback (round-1 atomic scatter) ============

__global__ void kB_deg(const int* __restrict__ dst, float* __restrict__ deg, int E) {
    int i = blockIdx.x * blockDim.x + threadIdx.x;
    if (i < E) atomicAdd(&deg[dst[i]], 1.0f);
}

__global__ void kB_dinv(float* __restrict__ deg, int n) {
    int i = blockIdx.x * blockDim.x + threadIdx.x;
    if (i < n) deg[i] = rsqrtf(deg[i] + 1.0f);
}

__global__ void kB_agg1(const int* __restrict__ src, const int* __restrict__ dst,
                        const float* __restrict__ dinv, const float* __restrict__ x,
                        float* __restrict__ agg1, int E) {
    int i = blockIdx.x * blockDim.x + threadIdx.x;
    if (i >= E) return;
    int s = src[i], d = dst[i];
    float w = dinv[s] * dinv[d];
    float2 xs = *reinterpret_cast<const float2*>(&x[2 * s]);
    atomicAdd(&agg1[2 * d],     w * xs.x);
    atomicAdd(&agg1[2 * d + 1], w * xs.y);
}

__global__ void kB_z(const float* __restrict__ agg1, const float* __restrict__ x,
                     const float* __restrict__ dinv,
                     const float* __restrict__ W1, const float* __restrict__ b1,
                     const float* __restrict__ W2, float* __restrict__ z, int n) {
    __shared__ float sW1[128], sb1[64], sW2[192];
    for (int t = threadIdx.x; t < 128; t += blockDim.x) sW1[t] = W1[t];
    for (int t = threadIdx.x; t < 64;  t += blockDim.x) sb1[t] = b1[t];
    for (int t = threadIdx.x; t < 192; t += blockDim.x) sW2[t] = W2[t];
    __syncthreads();
    int i = blockIdx.x * blockDim.x + threadIdx.x;
    if (i >= n) return;
    float di = dinv[i], w = di * di;
    float2 xs = *reinterpret_cast<const float2*>(&x[2 * i]);
    float a0 = agg1[2 * i]     + w * xs.x;
    float a1 = agg1[2 * i + 1] + w * xs.y;
    float z0 = 0.f, z1 = 0.f, z2 = 0.f;
#pragma unroll
    for (int j = 0; j < 64; ++j) {
        float h = fmaf(a0, sW1[j], fmaf(a1, sW1[64 + j], sb1[j]));
        h = fmaxf(h, 0.f);
        z0 = fmaf(h, sW2[3 * j],     z0);
        z1 = fmaf(h, sW2[3 * j + 1], z1);
        z2 = fmaf(h, sW2[3 * j + 2], z2);
    }
    z[3 * i] = z0; z[3 * i + 1] = z1; z[3 * i + 2] = z2;
}

__global__ void kB_agg2(const int* __restrict__ src, const int* __restrict__ dst,
                        const float* __restrict__ dinv, const float* __restrict__ z,
                        float* __restrict__ agg2, int E) {
    int i = blockIdx.x * blockDim.x + threadIdx.x;
    if (i >= E) return;
    int s = src[i], d = dst[i];
    float w = dinv[s] * dinv[d];
    atomicAdd(&agg2[3 * d],     w * z[3 * s]);
    atomicAdd(&agg2[3 * d + 1], w * z[3 * s + 1]);
    atomicAdd(&agg2[3 * d + 2], w * z[3 * s + 2]);
}

__global__ void kB_pool(const float* __restrict__ agg2, const float* __restrict__ z,
                        const float* __restrict__ dinv, const float* __restrict__ b2,
                        const int* __restrict__ batch,
                        float* __restrict__ pooled, float* __restrict__ cnt, int n) {
    int i = blockIdx.x * blockDim.x + threadIdx.x;
    if (i >= n) return;
    float di = dinv[i], w = di * di;
    float o0 = agg2[3 * i]     + w * z[3 * i]     + b2[0];
    float o1 = agg2[3 * i + 1] + w * z[3 * i + 1] + b2[1];
    float o2 = agg2[3 * i + 2] + w * z[3 * i + 2] + b2[2];
    int g = batch[i];
    atomicAdd(&pooled[3 * g],     o0);
    atomicAdd(&pooled[3 * g + 1], o1);
    atomicAdd(&pooled[3 * g + 2], o2);
    atomicAdd(&cnt[g], 1.0f);
}

// ============ launch ============

extern "C" void kernel_launch(void* const* d_in, const int* in_sizes, int n_in,
                              void* d_out, int out_size, void* d_ws, size_t ws_size,
                              hipStream_t stream) {
    const float* x     = (const float*)d_in[0];
    const int*   ei    = (const int*)  d_in[1];
    const int*   batch = (const int*)  d_in[2];
    const float* W1    = (const float*)d_in[3];
    const float* b1    = (const float*)d_in[4];
    const float* W2    = (const float*)d_in[5];
    const float* b2    = (const float*)d_in[6];
    float*       out   = (float*)d_out;

    const int n = in_sizes[2];
    const int E = in_sizes[1] / 2;
    const int G = out_size / 3;
    const int* src = ei;
    const int* dst = ei + E;
    const int B = 256;

    const int nbuk  = (n + BUCK - 1) >> SH;
    const int chunk = (E + NBLK - 1) / NBLK;
    const int M     = nbuk * NBLK;            // hist2d elements
    const int NB2   = (M + 255) / 256;        // scan blocks

    // Path-A workspace layout (4B units)
    size_t o = 0;
    size_t off_h2   = o; o += M;
    size_t off_rs2  = o; o += M;
    size_t off_bs   = o; o += 1024;
    size_t off_bse  = o; o += 1024;
    size_t off_part = o; o += E;
    size_t off_dinv = o; o += n;
    o = (o + 3) & ~(size_t)3;                 // 16B-align z
    size_t off_z    = o; o += (size_t)4 * n;
    size_t off_pool = o; o += (size_t)3 * G;
    size_t off_cnt  = o; o += G;
    size_t needA = o * 4;

    if (ws_size >= needA && nbuk <= NBUK_MAX && NB2 <= 1024) {
        int*    h2     = (int*)d_ws + off_h2;
        int*    rs2    = (int*)d_ws + off_rs2;
        int*    bs     = (int*)d_ws + off_bs;
        int*    bse    = (int*)d_ws + off_bse;
        int*    part   = (int*)d_ws + off_part;
        float*  dinv   = (float*)d_ws + off_dinv;
        float4* z      = (float4*)((float*)d_ws + off_z);
        float*  pooled = (float*)d_ws + off_pool;
        float*  cnt    = (float*)d_ws + off_cnt;

        hipMemsetAsync(pooled, 0, (size_t)4 * G * 4, stream);  // pooled+cnt contiguous
        k_pcount<<<NBLK, 256, 0, stream>>>(dst, h2, E, nbuk, chunk);
        k_scanA <<<NB2, 256, 0, stream>>>(h2, rs2, bs, M);
        k_scanB <<<1, 1024, 0, stream>>>(bs, bse, NB2);
        k_pfill <<<NBLK, 256, 0, stream>>>(src, dst, rs2, bse, part, E, nbuk, chunk);
        k_bdeg  <<<nbuk, 256, 0, stream>>>(part, rs2, bse, dinv, n, nbuk, E);
        k_bz    <<<nbuk, 256, 0, stream>>>(part, rs2, bse, dinv, x, W1, b1, W2, z, n, nbuk, E);
        k_bout  <<<nbuk, 256, 0, stream>>>(part, rs2, bse, dinv, z, b2, batch, pooled, cnt, n, nbuk, E);
        k_out   <<<(G + B - 1) / B, B, 0, stream>>>(pooled, cnt, out, G);
    } else {
        // fallback: atomic scatter path (needs (6n+4G)*4 bytes)
        float* ws     = (float*)d_ws;
        float* deg    = ws;
        float* agg1   = deg + n;
        float* agg2   = agg1 + 2 * (size_t)n;
        float* pooled = agg2 + 3 * (size_t)n;
        float* cnt    = pooled + 3 * (size_t)G;
        float* zf     = cnt + G;

        size_t zero_floats = (size_t)6 * n + (size_t)4 * G;
        hipMemsetAsync(ws, 0, zero_floats * sizeof(float), stream);
        kB_deg <<<(E + B - 1) / B, B, 0, stream>>>(dst, deg, E);
        kB_dinv<<<(n + B - 1) / B, B, 0, stream>>>(deg, n);
        kB_agg1<<<(E + B - 1) / B, B, 0, stream>>>(src, dst, deg, x, agg1, E);
        kB_z   <<<(n + B - 1) / B, B, 0, stream>>>(agg1, x, deg, W1, b1, W2, zf, n);
        kB_agg2<<<(E + B - 1) / B, B, 0, stream>>>(src, dst, deg, zf, agg2, E);
        kB_pool<<<(n + B - 1) / B, B, 0, stream>>>(agg2, zf, deg, b2, batch, pooled, cnt, n);
        k_out  <<<(G + B - 1) / B, B, 0, stream>>>(pooled, cnt, out, G);
    }
}

// Round 4
// 214.982 us; speedup vs baseline: 5.9394x; 1.3430x over previous
//
#include <hip/hip_runtime.h>

#define NBLK 512          // partition blocks
#define SH   9
#define BUCK 512          // nodes per bucket = 1<<SH
#define NBUK_MAX 512
#define BS   1024         // bucket-kernel block size (16 waves)

// ============ PATH A: bucket counting-sort + LDS accumulation ============

// Pass A: per-block LDS histogram of dst buckets -> hist2d[bucket*NBLK + block]
__global__ void k_pcount(const int* __restrict__ dst, int* __restrict__ hist2d,
                         int E, int nbuk, int chunk) {
    __shared__ int h[NBUK_MAX];
    for (int t = threadIdx.x; t < nbuk; t += 256) h[t] = 0;
    __syncthreads();
    int beg = blockIdx.x * chunk, end = min(beg + chunk, E);
    for (int i = beg + threadIdx.x; i < end; i += 256)
        atomicAdd(&h[dst[i] >> SH], 1);
    __syncthreads();
    for (int t = threadIdx.x; t < nbuk; t += 256)
        hist2d[t * NBLK + blockIdx.x] = h[t];
}

__global__ void k_scanA(const int* __restrict__ in, int* __restrict__ outp,
                        int* __restrict__ bsum, int M) {
    __shared__ int s[256];
    int t = threadIdx.x, i = blockIdx.x * 256 + t;
    int h = (i < M) ? in[i] : 0;
    s[t] = h; __syncthreads();
    for (int off = 1; off < 256; off <<= 1) {
        int v = (t >= off) ? s[t - off] : 0;
        __syncthreads();
        s[t] += v;
        __syncthreads();
    }
    if (i < M) outp[i] = s[t] - h;
    if (t == 255) bsum[blockIdx.x] = s[255];
}

__global__ void k_scanB(const int* __restrict__ bsum, int* __restrict__ bsum_ex, int NB) {
    __shared__ int s[1024];
    int t = threadIdx.x;
    int v = (t < NB) ? bsum[t] : 0;
    s[t] = v; __syncthreads();
    for (int off = 1; off < 1024; off <<= 1) {
        int u = (t >= off) ? s[t - off] : 0;
        __syncthreads();
        s[t] += u;
        __syncthreads();
    }
    if (t < NB) bsum_ex[t] = s[t] - v;
}

__device__ __forceinline__ int scan_off(const int* rs2, const int* bse, int j) {
    return rs2[j] + bse[j >> 8];
}

// Pass B: LDS cursors, write packed (src<<SH | dst_low) in bucket-partitioned order
__global__ void k_pfill(const int* __restrict__ src, const int* __restrict__ dst,
                        const int* __restrict__ rs2, const int* __restrict__ bse,
                        int* __restrict__ part, int E, int nbuk, int chunk) {
    __shared__ int cur[NBUK_MAX];
    for (int t = threadIdx.x; t < nbuk; t += 256) {
        int j = t * NBLK + blockIdx.x;
        cur[t] = scan_off(rs2, bse, j);
    }
    __syncthreads();
    int beg = blockIdx.x * chunk, end = min(beg + chunk, E);
    for (int i = beg + threadIdx.x; i < end; i += 256) {
        int d = dst[i];
        int pos = atomicAdd(&cur[d >> SH], 1);     // LDS atomic
        part[pos] = (src[i] << SH) | (d & (BUCK - 1));
    }
}

// per-bucket degree -> dinv; also xw = dinv * x (pre-scaled layer-1 payload)
__global__ void __launch_bounds__(BS) k_bdeg(
        const int* __restrict__ part, const int* __restrict__ rs2,
        const int* __restrict__ bse, const float* __restrict__ x,
        float* __restrict__ dinv, float2* __restrict__ xw,
        int n, int nbuk, int E) {
    __shared__ int c[BUCK];
    int b = blockIdx.x;
    for (int t = threadIdx.x; t < BUCK; t += BS) c[t] = 0;
    __syncthreads();
    int beg = scan_off(rs2, bse, b * NBLK);
    int end = (b + 1 < nbuk) ? scan_off(rs2, bse, (b + 1) * NBLK) : E;
    for (int i = beg + threadIdx.x; i < end; i += BS)
        atomicAdd(&c[part[i] & (BUCK - 1)], 1);
    __syncthreads();
    int base = b << SH;
    for (int t = threadIdx.x; t < BUCK; t += BS) {
        int node = base + t;
        if (node < n) {
            float di = rsqrtf((float)c[t] + 1.0f);
            dinv[node] = di;
            float2 xs = *reinterpret_cast<const float2*>(&x[2 * node]);
            xw[node] = make_float2(di * xs.x, di * xs.y);
        }
    }
}

// layer-1 bucket aggregation on xw (one 8B gather/edge) + fused MLP -> zw (float4)
__global__ void __launch_bounds__(BS) k_bz(
        const int* __restrict__ part, const int* __restrict__ rs2,
        const int* __restrict__ bse, const float* __restrict__ dinv,
        const float2* __restrict__ xw,
        const float* __restrict__ W1, const float* __restrict__ b1,
        const float* __restrict__ W2, float4* __restrict__ zw,
        int n, int nbuk, int E) {
    __shared__ float ax[BUCK], ay[BUCK];
    __shared__ float sW1[128], sb1[64], sW2[192];
    for (int t = threadIdx.x; t < 128; t += BS) sW1[t] = W1[t];
    for (int t = threadIdx.x; t < 64;  t += BS) sb1[t] = b1[t];
    for (int t = threadIdx.x; t < 192; t += BS) sW2[t] = W2[t];
    for (int t = threadIdx.x; t < BUCK; t += BS) { ax[t] = 0.f; ay[t] = 0.f; }
    __syncthreads();
    int b = blockIdx.x;
    int beg = scan_off(rs2, bse, b * NBLK);
    int end = (b + 1 < nbuk) ? scan_off(rs2, bse, (b + 1) * NBLK) : E;
    for (int i = beg + threadIdx.x; i < end; i += BS) {
        int e = part[i];
        float2 v = xw[e >> SH];
        int dl = e & (BUCK - 1);
        atomicAdd(&ax[dl], v.x);
        atomicAdd(&ay[dl], v.y);
    }
    __syncthreads();
    int base = b << SH;
    for (int t = threadIdx.x; t < BUCK; t += BS) {
        int node = base + t;
        if (node >= n) continue;
        float di = dinv[node];
        float2 xwn = xw[node];
        float a0 = di * (ax[t] + xwn.x);     // di * (sum_s xw_s + xw_i)
        float a1 = di * (ay[t] + xwn.y);
        float z0 = 0.f, z1 = 0.f, z2 = 0.f;
#pragma unroll
        for (int jj = 0; jj < 64; ++jj) {
            float h = fmaf(a0, sW1[jj], fmaf(a1, sW1[64 + jj], sb1[jj]));
            h = fmaxf(h, 0.f);
            z0 = fmaf(h, sW2[3 * jj],     z0);
            z1 = fmaf(h, sW2[3 * jj + 1], z1);
            z2 = fmaf(h, sW2[3 * jj + 2], z2);
        }
        zw[node] = make_float4(di * z0, di * z1, di * z2, 0.f);  // pre-scaled layer-2 payload
    }
}

// layer-2 bucket aggregation on zw (one 16B gather/edge) + epilogue + wave pooling
__global__ void __launch_bounds__(BS) k_bout(
        const int* __restrict__ part, const int* __restrict__ rs2,
        const int* __restrict__ bse, const float* __restrict__ dinv,
        const float4* __restrict__ zw, const float* __restrict__ b2,
        const int* __restrict__ batch,
        float* __restrict__ pooled, float* __restrict__ cnt,
        int n, int nbuk, int E) {
    __shared__ float a0s[BUCK], a1s[BUCK], a2s[BUCK];
    for (int t = threadIdx.x; t < BUCK; t += BS) { a0s[t] = 0.f; a1s[t] = 0.f; a2s[t] = 0.f; }
    __syncthreads();
    int b = blockIdx.x;
    int beg = scan_off(rs2, bse, b * NBLK);
    int end = (b + 1 < nbuk) ? scan_off(rs2, bse, (b + 1) * NBLK) : E;
    for (int i = beg + threadIdx.x; i < end; i += BS) {
        int e = part[i];
        float4 zs = zw[e >> SH];
        int dl = e & (BUCK - 1);
        atomicAdd(&a0s[dl], zs.x);
        atomicAdd(&a1s[dl], zs.y);
        atomicAdd(&a2s[dl], zs.z);
    }
    __syncthreads();
    float bb0 = b2[0], bb1 = b2[1], bb2 = b2[2];
    int base = b << SH;
    for (int t = threadIdx.x; t < BUCK; t += BS) {
        int node = base + t;
        float o0 = 0.f, o1 = 0.f, o2 = 0.f, vc = 0.f;
        int g = -1;
        if (node < n) {
            float di = dinv[node];
            float4 zs = zw[node];
            o0 = fmaf(di, a0s[t] + zs.x, bb0);   // di*(sum_s zw_s + zw_i) + b2
            o1 = fmaf(di, a1s[t] + zs.y, bb1);
            o2 = fmaf(di, a2s[t] + zs.z, bb2);
            vc = 1.f;
            g = batch[node];
        }
        int g0 = __shfl(g, 0);
        bool uni = __all(g == g0);
        if (uni) {
            for (int off = 32; off; off >>= 1) {
                o0 += __shfl_down(o0, off);
                o1 += __shfl_down(o1, off);
                o2 += __shfl_down(o2, off);
                vc += __shfl_down(vc, off);
            }
            if ((threadIdx.x & 63) == 0 && g0 >= 0) {
                atomicAdd(&pooled[3 * g0],     o0);
                atomicAdd(&pooled[3 * g0 + 1], o1);
                atomicAdd(&pooled[3 * g0 + 2], o2);
                atomicAdd(&cnt[g0], vc);
            }
        } else if (g >= 0) {
            atomicAdd(&pooled[3 * g],     o0);
            atomicAdd(&pooled[3 * g + 1], o1);
            atomicAdd(&pooled[3 * g + 2], o2);
            atomicAdd(&cnt[g], 1.f);
        }
    }
}

__global__ void k_out(const float* __restrict__ pooled, const float* __restrict__ cnt,
                      float* __restrict__ out, int G) {
    int g = blockIdx.x * blockDim.x + threadIdx.x;
    if (g >= G) return;
    float c = fmaxf(cnt[g], 1.0f);
    float p0 = pooled[3 * g] / c, p1 = pooled[3 * g + 1] / c, p2 = pooled[3 * g + 2] / c;
    float m = fmaxf(p0, fmaxf(p1, p2));
    float s = expf(p0 - m) + expf(p1 - m) + expf(p2 - m);
    float l = logf(s);
    out[3 * g]     = p0 - m - l;
    out[3 * g + 1] = p1 - m - l;
    out[3 * g + 2] = p2 - m - l;
}

// ============ PATH B: fallback (atomic scatter) ============

__global__ void kB_deg(const int* __restrict__ dst, float* __restrict__ deg, int E) {
    int i = blockIdx.x * blockDim.x + threadIdx.x;
    if (i < E) atomicAdd(&deg[dst[i]], 1.0f);
}

__global__ void kB_dinv(float* __restrict__ deg, int n) {
    int i = blockIdx.x * blockDim.x + threadIdx.x;
    if (i < n) deg[i] = rsqrtf(deg[i] + 1.0f);
}

__global__ void kB_agg1(const int* __restrict__ src, const int* __restrict__ dst,
                        const float* __restrict__ dinv, const float* __restrict__ x,
                        float* __restrict__ agg1, int E) {
    int i = blockIdx.x * blockDim.x + threadIdx.x;
    if (i >= E) return;
    int s = src[i], d = dst[i];
    float w = dinv[s] * dinv[d];
    float2 xs = *reinterpret_cast<const float2*>(&x[2 * s]);
    atomicAdd(&agg1[2 * d],     w * xs.x);
    atomicAdd(&agg1[2 * d + 1], w * xs.y);
}

__global__ void kB_z(const float* __restrict__ agg1, const float* __restrict__ x,
                     const float* __restrict__ dinv,
                     const float* __restrict__ W1, const float* __restrict__ b1,
                     const float* __restrict__ W2, float* __restrict__ z, int n) {
    __shared__ float sW1[128], sb1[64], sW2[192];
    for (int t = threadIdx.x; t < 128; t += blockDim.x) sW1[t] = W1[t];
    for (int t = threadIdx.x; t < 64;  t += blockDim.x) sb1[t] = b1[t];
    for (int t = threadIdx.x; t < 192; t += blockDim.x) sW2[t] = W2[t];
    __syncthreads();
    int i = blockIdx.x * blockDim.x + threadIdx.x;
    if (i >= n) return;
    float di = dinv[i], w = di * di;
    float2 xs = *reinterpret_cast<const float2*>(&x[2 * i]);
    float a0 = agg1[2 * i]     + w * xs.x;
    float a1 = agg1[2 * i + 1] + w * xs.y;
    float z0 = 0.f, z1 = 0.f, z2 = 0.f;
#pragma unroll
    for (int j = 0; j < 64; ++j) {
        float h = fmaf(a0, sW1[j], fmaf(a1, sW1[64 + j], sb1[j]));
        h = fmaxf(h, 0.f);
        z0 = fmaf(h, sW2[3 * j],     z0);
        z1 = fmaf(h, sW2[3 * j + 1], z1);
        z2 = fmaf(h, sW2[3 * j + 2], z2);
    }
    z[3 * i] = z0; z[3 * i + 1] = z1; z[3 * i + 2] = z2;
}

__global__ void kB_agg2(const int* __restrict__ src, const int* __restrict__ dst,
                        const float* __restrict__ dinv, const float* __restrict__ z,
                        float* __restrict__ agg2, int E) {
    int i = blockIdx.x * blockDim.x + threadIdx.x;
    if (i >= E) return;
    int s = src[i], d = dst[i];
    float w = dinv[s] * dinv[d];
    atomicAdd(&agg2[3 * d],     w * z[3 * s]);
    atomicAdd(&agg2[3 * d + 1], w * z[3 * s + 1]);
    atomicAdd(&agg2[3 * d + 2], w * z[3 * s + 2]);
}

__global__ void kB_pool(const float* __restrict__ agg2, const float* __restrict__ z,
                        const float* __restrict__ dinv, const float* __restrict__ b2,
                        const int* __restrict__ batch,
                        float* __restrict__ pooled, float* __restrict__ cnt, int n) {
    int i = blockIdx.x * blockDim.x + threadIdx.x;
    if (i >= n) return;
    float di = dinv[i], w = di * di;
    float o0 = agg2[3 * i]     + w * z[3 * i]     + b2[0];
    float o1 = agg2[3 * i + 1] + w * z[3 * i + 1] + b2[1];
    float o2 = agg2[3 * i + 2] + w * z[3 * i + 2] + b2[2];
    int g = batch[i];
    atomicAdd(&pooled[3 * g],     o0);
    atomicAdd(&pooled[3 * g + 1], o1);
    atomicAdd(&pooled[3 * g + 2], o2);
    atomicAdd(&cnt[g], 1.0f);
}

// ============ launch ============

extern "C" void kernel_launch(void* const* d_in, const int* in_sizes, int n_in,
                              void* d_out, int out_size, void* d_ws, size_t ws_size,
                              hipStream_t stream) {
    const float* x     = (const float*)d_in[0];
    const int*   ei    = (const int*)  d_in[1];
    const int*   batch = (const int*)  d_in[2];
    const float* W1    = (const float*)d_in[3];
    const float* b1    = (const float*)d_in[4];
    const float* W2    = (const float*)d_in[5];
    const float* b2    = (const float*)d_in[6];
    float*       out   = (float*)d_out;

    const int n = in_sizes[2];
    const int E = in_sizes[1] / 2;
    const int G = out_size / 3;
    const int* src = ei;
    const int* dst = ei + E;
    const int B = 256;

    const int nbuk  = (n + BUCK - 1) >> SH;
    const int chunk = (E + NBLK - 1) / NBLK;
    const int M     = nbuk * NBLK;
    const int NB2   = (M + 255) / 256;

    // Path-A workspace layout (4B units)
    size_t o = 0;
    size_t off_h2   = o; o += M;
    size_t off_rs2  = o; o += M;
    size_t off_bs   = o; o += 1024;
    size_t off_bse  = o; o += 1024;
    size_t off_part = o; o += E;
    size_t off_dinv = o; o += n;
    size_t off_xw   = o; o += (size_t)2 * n;
    o = (o + 3) & ~(size_t)3;                 // 16B-align zw
    size_t off_zw   = o; o += (size_t)4 * n;
    size_t off_pool = o; o += (size_t)3 * G;
    size_t off_cnt  = o; o += G;
    size_t needA = o * 4;

    if (ws_size >= needA && nbuk <= NBUK_MAX && NB2 <= 1024) {
        int*    h2     = (int*)d_ws + off_h2;
        int*    rs2    = (int*)d_ws + off_rs2;
        int*    bs     = (int*)d_ws + off_bs;
        int*    bse    = (int*)d_ws + off_bse;
        int*    part   = (int*)d_ws + off_part;
        float*  dinv   = (float*)d_ws + off_dinv;
        float2* xw     = (float2*)((float*)d_ws + off_xw);
        float4* zw     = (float4*)((float*)d_ws + off_zw);
        float*  pooled = (float*)d_ws + off_pool;
        float*  cnt    = (float*)d_ws + off_cnt;

        hipMemsetAsync(pooled, 0, (size_t)4 * G * 4, stream);  // pooled+cnt contiguous
        k_pcount<<<NBLK, 256, 0, stream>>>(dst, h2, E, nbuk, chunk);
        k_scanA <<<NB2, 256, 0, stream>>>(h2, rs2, bs, M);
        k_scanB <<<1, 1024, 0, stream>>>(bs, bse, NB2);
        k_pfill <<<NBLK, 256, 0, stream>>>(src, dst, rs2, bse, part, E, nbuk, chunk);
        k_bdeg  <<<nbuk, BS, 0, stream>>>(part, rs2, bse, x, dinv, xw, n, nbuk, E);
        k_bz    <<<nbuk, BS, 0, stream>>>(part, rs2, bse, dinv, xw, W1, b1, W2, zw, n, nbuk, E);
        k_bout  <<<nbuk, BS, 0, stream>>>(part, rs2, bse, dinv, zw, b2, batch, pooled, cnt, n, nbuk, E);
        k_out   <<<(G + B - 1) / B, B, 0, stream>>>(pooled, cnt, out, G);
    } else {
        float* ws     = (float*)d_ws;
        float* deg    = ws;
        float* agg1   = deg + n;
        float* agg2   = agg1 + 2 * (size_t)n;
        float* pooled = agg2 + 3 * (size_t)n;
        float* cnt    = pooled + 3 * (size_t)G;
        float* zf     = cnt + G;

        size_t zero_floats = (size_t)6 * n + (size_t)4 * G;
        hipMemsetAsync(ws, 0, zero_floats * sizeof(float), stream);
        kB_deg <<<(E + B - 1) / B, B, 0, stream>>>(dst, deg, E);
        kB_dinv<<<(n + B - 1) / B, B, 0, stream>>>(deg, n);
        kB_agg1<<<(E + B - 1) / B, B, 0, stream>>>(src, dst, deg, x, agg1, E);
        kB_z   <<<(n + B - 1) / B, B, 0, stream>>>(agg1, x, deg, W1, b1, W2, zf, n);
        kB_agg2<<<(E + B - 1) / B, B, 0, stream>>>(src, dst, deg, zf, agg2, E);
        kB_pool<<<(n + B - 1) / B, B, 0, stream>>>(agg2, zf, deg, b2, batch, pooled, cnt, n);
        k_out  <<<(G + B - 1) / B, B, 0, stream>>>(pooled, cnt, out, G);
    }
}

// Round 5
// 186.027 us; speedup vs baseline: 6.8638x; 1.1556x over previous
//
#include <hip/hip_runtime.h>

#define NBLK 512          // partition blocks
#define SH   9
#define BUCK 512          // nodes per bucket = 1<<SH
#define NBUK_MAX 512

// ============ PATH A: bucket sort -> exact CSR -> register-accum gathers ============

// Pass A: per-block LDS histogram of dst buckets -> hist2d[bucket*NBLK + block]
__global__ void k_pcount(const int* __restrict__ dst, int* __restrict__ hist2d,
                         int E, int nbuk, int chunk) {
    __shared__ int h[NBUK_MAX];
    for (int t = threadIdx.x; t < nbuk; t += 256) h[t] = 0;
    __syncthreads();
    int beg = blockIdx.x * chunk, end = min(beg + chunk, E);
    for (int i = beg + threadIdx.x; i < end; i += 256)
        atomicAdd(&h[dst[i] >> SH], 1);
    __syncthreads();
    for (int t = threadIdx.x; t < nbuk; t += 256)
        hist2d[t * NBLK + blockIdx.x] = h[t];
}

__global__ void k_scanA(const int* __restrict__ in, int* __restrict__ outp,
                        int* __restrict__ bsum, int M) {
    __shared__ int s[256];
    int t = threadIdx.x, i = blockIdx.x * 256 + t;
    int h = (i < M) ? in[i] : 0;
    s[t] = h; __syncthreads();
    for (int off = 1; off < 256; off <<= 1) {
        int v = (t >= off) ? s[t - off] : 0;
        __syncthreads();
        s[t] += v;
        __syncthreads();
    }
    if (i < M) outp[i] = s[t] - h;
    if (t == 255) bsum[blockIdx.x] = s[255];
}

__global__ void k_scanB(const int* __restrict__ bsum, int* __restrict__ bsum_ex, int NB) {
    __shared__ int s[1024];
    int t = threadIdx.x;
    int v = (t < NB) ? bsum[t] : 0;
    s[t] = v; __syncthreads();
    for (int off = 1; off < 1024; off <<= 1) {
        int u = (t >= off) ? s[t - off] : 0;
        __syncthreads();
        s[t] += u;
        __syncthreads();
    }
    if (t < NB) bsum_ex[t] = s[t] - v;
}

__device__ __forceinline__ int scan_off(const int* rs2, const int* bse, int j) {
    return rs2[j] + bse[j >> 8];
}

// Pass B: LDS cursors, write packed (src<<SH | dst_low) in bucket-partitioned order
__global__ void k_pfill(const int* __restrict__ src, const int* __restrict__ dst,
                        const int* __restrict__ rs2, const int* __restrict__ bse,
                        int* __restrict__ part, int E, int nbuk, int chunk) {
    __shared__ int cur[NBUK_MAX];
    for (int t = threadIdx.x; t < nbuk; t += 256) {
        int j = t * NBLK + blockIdx.x;
        cur[t] = scan_off(rs2, bse, j);
    }
    __syncthreads();
    int beg = blockIdx.x * chunk, end = min(beg + chunk, E);
    for (int i = beg + threadIdx.x; i < end; i += 256) {
        int d = dst[i];
        int pos = atomicAdd(&cur[d >> SH], 1);     // LDS atomic
        part[pos] = (src[i] << SH) | (d & (BUCK - 1));
    }
}

// per bucket: per-node hist -> scan -> scatter src into dst-sorted part2;
// also rowstart (absolute), dinv, xw = dinv*x
__global__ void __launch_bounds__(512) k_prep(
        const int* __restrict__ part, const int* __restrict__ rs2,
        const int* __restrict__ bse, const float* __restrict__ x,
        int* __restrict__ part2, int* __restrict__ rowstart,
        float* __restrict__ dinv, float2* __restrict__ xw,
        int n, int nbuk, int E) {
    __shared__ int hist[BUCK];
    __shared__ int s[BUCK];
    __shared__ int cur[BUCK];
    int t = threadIdx.x, b = blockIdx.x;
    hist[t] = 0;
    __syncthreads();
    int beg = scan_off(rs2, bse, b * NBLK);
    int end = (b + 1 < nbuk) ? scan_off(rs2, bse, (b + 1) * NBLK) : E;
    for (int i = beg + t; i < end; i += 512)
        atomicAdd(&hist[part[i] & (BUCK - 1)], 1);
    __syncthreads();
    // inclusive Hillis-Steele scan of hist into s
    s[t] = hist[t];
    __syncthreads();
    for (int d = 1; d < 512; d <<= 1) {
        int v = (t >= d) ? s[t - d] : 0;
        __syncthreads();
        s[t] += v;
        __syncthreads();
    }
    int excl = s[t] - hist[t];
    cur[t] = beg + excl;
    int node = (b << SH) + t;
    rowstart[node] = beg + excl;
    if (node < n) {
        float di = rsqrtf((float)hist[t] + 1.0f);
        dinv[node] = di;
        float2 xs = *reinterpret_cast<const float2*>(&x[2 * node]);
        xw[node] = make_float2(di * xs.x, di * xs.y);
    }
    __syncthreads();
    for (int i = beg + t; i < end; i += 512) {
        int e = part[i];
        int p = atomicAdd(&cur[e & (BUCK - 1)], 1);
        part2[p] = e >> SH;                        // src, in dst-sorted position
    }
}

// layer-1: per-node register accumulation over CSR run + fused MLP -> zw
__global__ void __launch_bounds__(256) k_bz(
        const int* __restrict__ part2, const int* __restrict__ rowstart,
        const float* __restrict__ dinv, const float2* __restrict__ xw,
        const float* __restrict__ W1, const float* __restrict__ b1,
        const float* __restrict__ W2, float4* __restrict__ zw, int n) {
    __shared__ float sW1[128], sb1[64], sW2[192];
    for (int t = threadIdx.x; t < 128; t += 256) sW1[t] = W1[t];
    for (int t = threadIdx.x; t < 64;  t += 256) sb1[t] = b1[t];
    for (int t = threadIdx.x; t < 192; t += 256) sW2[t] = W2[t];
    __syncthreads();
    int i = blockIdx.x * 256 + threadIdx.x;
    if (i >= n) return;
    int beg = rowstart[i], end = rowstart[i + 1];
    float2 self = xw[i];
    float a0 = self.x, a1 = self.y;                // self-loop term
    int e = beg;
    for (; e + 4 <= end; e += 4) {                 // 4 independent gathers in flight
        int s0 = part2[e], s1 = part2[e + 1], s2 = part2[e + 2], s3 = part2[e + 3];
        float2 v0 = xw[s0], v1 = xw[s1], v2 = xw[s2], v3 = xw[s3];
        a0 += (v0.x + v1.x) + (v2.x + v3.x);
        a1 += (v0.y + v1.y) + (v2.y + v3.y);
    }
    for (; e < end; ++e) {
        float2 v = xw[part2[e]];
        a0 += v.x; a1 += v.y;
    }
    float di = dinv[i];
    a0 *= di; a1 *= di;
    float z0 = 0.f, z1 = 0.f, z2 = 0.f;
#pragma unroll
    for (int jj = 0; jj < 64; ++jj) {
        float h = fmaf(a0, sW1[jj], fmaf(a1, sW1[64 + jj], sb1[jj]));
        h = fmaxf(h, 0.f);
        z0 = fmaf(h, sW2[3 * jj],     z0);
        z1 = fmaf(h, sW2[3 * jj + 1], z1);
        z2 = fmaf(h, sW2[3 * jj + 2], z2);
    }
    zw[i] = make_float4(di * z0, di * z1, di * z2, 0.f);   // pre-scaled payload
}

// layer-2: per-node register accumulation over CSR run + epilogue + wave pooling
__global__ void __launch_bounds__(256) k_bout(
        const int* __restrict__ part2, const int* __restrict__ rowstart,
        const float* __restrict__ dinv, const float4* __restrict__ zw,
        const float* __restrict__ b2, const int* __restrict__ batch,
        float* __restrict__ pooled, float* __restrict__ cnt, int n) {
    int i = blockIdx.x * 256 + threadIdx.x;
    float o0 = 0.f, o1 = 0.f, o2 = 0.f, vc = 0.f;
    int g = -1;
    if (i < n) {
        int beg = rowstart[i], end = rowstart[i + 1];
        float4 self = zw[i];
        float a0 = self.x, a1 = self.y, a2 = self.z;
        int e = beg;
        for (; e + 4 <= end; e += 4) {
            int s0 = part2[e], s1 = part2[e + 1], s2 = part2[e + 2], s3 = part2[e + 3];
            float4 v0 = zw[s0], v1 = zw[s1], v2 = zw[s2], v3 = zw[s3];
            a0 += (v0.x + v1.x) + (v2.x + v3.x);
            a1 += (v0.y + v1.y) + (v2.y + v3.y);
            a2 += (v0.z + v1.z) + (v2.z + v3.z);
        }
        for (; e < end; ++e) {
            float4 v = zw[part2[e]];
            a0 += v.x; a1 += v.y; a2 += v.z;
        }
        float di = dinv[i];
        o0 = fmaf(di, a0, b2[0]);
        o1 = fmaf(di, a1, b2[1]);
        o2 = fmaf(di, a2, b2[2]);
        vc = 1.f;
        g = batch[i];
    }
    int g0 = __shfl(g, 0);
    bool uni = __all(g == g0);
    if (uni) {
        for (int off = 32; off; off >>= 1) {
            o0 += __shfl_down(o0, off);
            o1 += __shfl_down(o1, off);
            o2 += __shfl_down(o2, off);
            vc += __shfl_down(vc, off);
        }
        if ((threadIdx.x & 63) == 0 && g0 >= 0) {
            atomicAdd(&pooled[3 * g0],     o0);
            atomicAdd(&pooled[3 * g0 + 1], o1);
            atomicAdd(&pooled[3 * g0 + 2], o2);
            atomicAdd(&cnt[g0], vc);
        }
    } else if (g >= 0) {
        atomicAdd(&pooled[3 * g],     o0);
        atomicAdd(&pooled[3 * g + 1], o1);
        atomicAdd(&pooled[3 * g + 2], o2);
        atomicAdd(&cnt[g], 1.f);
    }
}

__global__ void k_out(const float* __restrict__ pooled, const float* __restrict__ cnt,
                      float* __restrict__ out, int G) {
    int g = blockIdx.x * blockDim.x + threadIdx.x;
    if (g >= G) return;
    float c = fmaxf(cnt[g], 1.0f);
    float p0 = pooled[3 * g] / c, p1 = pooled[3 * g + 1] / c, p2 = pooled[3 * g + 2] / c;
    float m = fmaxf(p0, fmaxf(p1, p2));
    float s = expf(p0 - m) + expf(p1 - m) + expf(p2 - m);
    float l = logf(s);
    out[3 * g]     = p0 - m - l;
    out[3 * g + 1] = p1 - m - l;
    out[3 * g + 2] = p2 - m - l;
}

// ============ PATH B: fallback (atomic scatter) ============

__global__ void kB_deg(const int* __restrict__ dst, float* __restrict__ deg, int E) {
    int i = blockIdx.x * blockDim.x + threadIdx.x;
    if (i < E) atomicAdd(&deg[dst[i]], 1.0f);
}

__global__ void kB_dinv(float* __restrict__ deg, int n) {
    int i = blockIdx.x * blockDim.x + threadIdx.x;
    if (i < n) deg[i] = rsqrtf(deg[i] + 1.0f);
}

__global__ void kB_agg1(const int* __restrict__ src, const int* __restrict__ dst,
                        const float* __restrict__ dinv, const float* __restrict__ x,
                        float* __restrict__ agg1, int E) {
    int i = blockIdx.x * blockDim.x + threadIdx.x;
    if (i >= E) return;
    int s = src[i], d = dst[i];
    float w = dinv[s] * dinv[d];
    float2 xs = *reinterpret_cast<const float2*>(&x[2 * s]);
    atomicAdd(&agg1[2 * d],     w * xs.x);
    atomicAdd(&agg1[2 * d + 1], w * xs.y);
}

__global__ void kB_z(const float* __restrict__ agg1, const float* __restrict__ x,
                     const float* __restrict__ dinv,
                     const float* __restrict__ W1, const float* __restrict__ b1,
                     const float* __restrict__ W2, float* __restrict__ z, int n) {
    __shared__ float sW1[128], sb1[64], sW2[192];
    for (int t = threadIdx.x; t < 128; t += blockDim.x) sW1[t] = W1[t];
    for (int t = threadIdx.x; t < 64;  t += blockDim.x) sb1[t] = b1[t];
    for (int t = threadIdx.x; t < 192; t += blockDim.x) sW2[t] = W2[t];
    __syncthreads();
    int i = blockIdx.x * blockDim.x + threadIdx.x;
    if (i >= n) return;
    float di = dinv[i], w = di * di;
    float2 xs = *reinterpret_cast<const float2*>(&x[2 * i]);
    float a0 = agg1[2 * i]     + w * xs.x;
    float a1 = agg1[2 * i + 1] + w * xs.y;
    float z0 = 0.f, z1 = 0.f, z2 = 0.f;
#pragma unroll
    for (int j = 0; j < 64; ++j) {
        float h = fmaf(a0, sW1[j], fmaf(a1, sW1[64 + j], sb1[j]));
        h = fmaxf(h, 0.f);
        z0 = fmaf(h, sW2[3 * j],     z0);
        z1 = fmaf(h, sW2[3 * j + 1], z1);
        z2 = fmaf(h, sW2[3 * j + 2], z2);
    }
    z[3 * i] = z0; z[3 * i + 1] = z1; z[3 * i + 2] = z2;
}

__global__ void kB_agg2(const int* __restrict__ src, const int* __restrict__ dst,
                        const float* __restrict__ dinv, const float* __restrict__ z,
                        float* __restrict__ agg2, int E) {
    int i = blockIdx.x * blockDim.x + threadIdx.x;
    if (i >= E) return;
    int s = src[i], d = dst[i];
    float w = dinv[s] * dinv[d];
    atomicAdd(&agg2[3 * d],     w * z[3 * s]);
    atomicAdd(&agg2[3 * d + 1], w * z[3 * s + 1]);
    atomicAdd(&agg2[3 * d + 2], w * z[3 * s + 2]);
}

__global__ void kB_pool(const float* __restrict__ agg2, const float* __restrict__ z,
                        const float* __restrict__ dinv, const float* __restrict__ b2,
                        const int* __restrict__ batch,
                        float* __restrict__ pooled, float* __restrict__ cnt, int n) {
    int i = blockIdx.x * blockDim.x + threadIdx.x;
    if (i >= n) return;
    float di = dinv[i], w = di * di;
    float o0 = agg2[3 * i]     + w * z[3 * i]     + b2[0];
    float o1 = agg2[3 * i + 1] + w * z[3 * i + 1] + b2[1];
    float o2 = agg2[3 * i + 2] + w * z[3 * i + 2] + b2[2];
    int g = batch[i];
    atomicAdd(&pooled[3 * g],     o0);
    atomicAdd(&pooled[3 * g + 1], o1);
    atomicAdd(&pooled[3 * g + 2], o2);
    atomicAdd(&cnt[g], 1.0f);
}

// ============ launch ============

extern "C" void kernel_launch(void* const* d_in, const int* in_sizes, int n_in,
                              void* d_out, int out_size, void* d_ws, size_t ws_size,
                              hipStream_t stream) {
    const float* x     = (const float*)d_in[0];
    const int*   ei    = (const int*)  d_in[1];
    const int*   batch = (const int*)  d_in[2];
    const float* W1    = (const float*)d_in[3];
    const float* b1    = (const float*)d_in[4];
    const float* W2    = (const float*)d_in[5];
    const float* b2    = (const float*)d_in[6];
    float*       out   = (float*)d_out;

    const int n = in_sizes[2];
    const int E = in_sizes[1] / 2;
    const int G = out_size / 3;
    const int* src = ei;
    const int* dst = ei + E;
    const int B = 256;

    const int nbuk  = (n + BUCK - 1) >> SH;
    const int chunk = (E + NBLK - 1) / NBLK;
    const int M     = nbuk * NBLK;
    const int NB2   = (M + 255) / 256;

    // Path-A workspace layout (4B units)
    size_t o = 0;
    size_t off_h2   = o; o += M;
    size_t off_rs2  = o; o += M;
    size_t off_bs   = o; o += 1024;
    size_t off_bse  = o; o += 1024;
    size_t off_part = o; o += E;
    size_t off_p2   = o; o += E;
    size_t off_row  = o; o += (size_t)nbuk * BUCK + 1;
    size_t off_dinv = o; o += n;
    size_t off_xw   = o; o += (size_t)2 * n;
    o = (o + 3) & ~(size_t)3;                 // 16B-align zw
    size_t off_zw   = o; o += (size_t)4 * n;
    size_t off_pool = o; o += (size_t)3 * G;
    size_t off_cnt  = o; o += G;
    size_t needA = o * 4;

    if (ws_size >= needA && nbuk <= NBUK_MAX && NB2 <= 1024) {
        int*    h2     = (int*)d_ws + off_h2;
        int*    rs2    = (int*)d_ws + off_rs2;
        int*    bs     = (int*)d_ws + off_bs;
        int*    bse    = (int*)d_ws + off_bse;
        int*    part   = (int*)d_ws + off_part;
        int*    part2  = (int*)d_ws + off_p2;
        int*    row    = (int*)d_ws + off_row;
        float*  dinv   = (float*)d_ws + off_dinv;
        float2* xw     = (float2*)((float*)d_ws + off_xw);
        float4* zw     = (float4*)((float*)d_ws + off_zw);
        float*  pooled = (float*)d_ws + off_pool;
        float*  cnt    = (float*)d_ws + off_cnt;

        hipMemsetAsync(pooled, 0, (size_t)4 * G * 4, stream);  // pooled+cnt contiguous
        k_pcount<<<NBLK, 256, 0, stream>>>(dst, h2, E, nbuk, chunk);
        k_scanA <<<NB2, 256, 0, stream>>>(h2, rs2, bs, M);
        k_scanB <<<1, 1024, 0, stream>>>(bs, bse, NB2);
        k_pfill <<<NBLK, 256, 0, stream>>>(src, dst, rs2, bse, part, E, nbuk, chunk);
        k_prep  <<<nbuk, 512, 0, stream>>>(part, rs2, bse, x, part2, row, dinv, xw, n, nbuk, E);
        k_bz    <<<(n + 255) / 256, 256, 0, stream>>>(part2, row, dinv, xw, W1, b1, W2, zw, n);
        k_bout  <<<(n + 255) / 256, 256, 0, stream>>>(part2, row, dinv, zw, b2, batch, pooled, cnt, n);
        k_out   <<<(G + B - 1) / B, B, 0, stream>>>(pooled, cnt, out, G);
    } else {
        float* ws     = (float*)d_ws;
        float* deg    = ws;
        float* agg1   = deg + n;
        float* agg2   = agg1 + 2 * (size_t)n;
        float* pooled = agg2 + 3 * (size_t)n;
        float* cnt    = pooled + 3 * (size_t)G;
        float* zf     = cnt + G;

        size_t zero_floats = (size_t)6 * n + (size_t)4 * G;
        hipMemsetAsync(ws, 0, zero_floats * sizeof(float), stream);
        kB_deg <<<(E + B - 1) / B, B, 0, stream>>>(dst, deg, E);
        kB_dinv<<<(n + B - 1) / B, B, 0, stream>>>(deg, n);
        kB_agg1<<<(E + B - 1) / B, B, 0, stream>>>(src, dst, deg, x, agg1, E);
        kB_z   <<<(n + B - 1) / B, B, 0, stream>>>(agg1, x, deg, W1, b1, W2, zf, n);
        kB_agg2<<<(E + B - 1) / B, B, 0, stream>>>(src, dst, deg, zf, agg2, E);
        kB_pool<<<(n + B - 1) / B, B, 0, stream>>>(agg2, zf, deg, b2, batch, pooled, cnt, n);
        k_out  <<<(G + B - 1) / B, B, 0, stream>>>(pooled, cnt, out, G);
    }
}

// Round 6
// 156.908 us; speedup vs baseline: 8.1376x; 1.1856x over previous
//
#include <hip/hip_runtime.h>

#define NBLK 512          // partition blocks
#define SH   9
#define BUCK 512          // nodes per bucket = 1<<SH
#define NBUK_MAX 512

// ============ PATH A: bucket sort -> exact CSR -> 4-lane register gathers ============

// Pass A: per-block LDS histogram of dst buckets -> hist2d[bucket*NBLK + block]
__global__ void k_pcount(const int* __restrict__ dst, int* __restrict__ hist2d,
                         int E, int nbuk, int chunk) {
    __shared__ int h[NBUK_MAX];
    for (int t = threadIdx.x; t < nbuk; t += 256) h[t] = 0;
    __syncthreads();
    int beg = blockIdx.x * chunk, end = min(beg + chunk, E);
    for (int i = beg + threadIdx.x; i < end; i += 256)
        atomicAdd(&h[dst[i] >> SH], 1);
    __syncthreads();
    for (int t = threadIdx.x; t < nbuk; t += 256)
        hist2d[t * NBLK + blockIdx.x] = h[t];
}

__global__ void k_scanA(const int* __restrict__ in, int* __restrict__ outp,
                        int* __restrict__ bsum, int M) {
    __shared__ int s[256];
    int t = threadIdx.x, i = blockIdx.x * 256 + t;
    int h = (i < M) ? in[i] : 0;
    s[t] = h; __syncthreads();
    for (int off = 1; off < 256; off <<= 1) {
        int v = (t >= off) ? s[t - off] : 0;
        __syncthreads();
        s[t] += v;
        __syncthreads();
    }
    if (i < M) outp[i] = s[t] - h;
    if (t == 255) bsum[blockIdx.x] = s[255];
}

__global__ void k_scanB(const int* __restrict__ bsum, int* __restrict__ bsum_ex, int NB) {
    __shared__ int s[1024];
    int t = threadIdx.x;
    int v = (t < NB) ? bsum[t] : 0;
    s[t] = v; __syncthreads();
    for (int off = 1; off < 1024; off <<= 1) {
        int u = (t >= off) ? s[t - off] : 0;
        __syncthreads();
        s[t] += u;
        __syncthreads();
    }
    if (t < NB) bsum_ex[t] = s[t] - v;
}

__device__ __forceinline__ int scan_off(const int* rs2, const int* bse, int j) {
    return rs2[j] + bse[j >> 8];
}

// Pass B: LDS cursors, write packed (src<<SH | dst_low) in bucket-partitioned order
__global__ void k_pfill(const int* __restrict__ src, const int* __restrict__ dst,
                        const int* __restrict__ rs2, const int* __restrict__ bse,
                        int* __restrict__ part, int E, int nbuk, int chunk) {
    __shared__ int cur[NBUK_MAX];
    for (int t = threadIdx.x; t < nbuk; t += 256) {
        int j = t * NBLK + blockIdx.x;
        cur[t] = scan_off(rs2, bse, j);
    }
    __syncthreads();
    int beg = blockIdx.x * chunk, end = min(beg + chunk, E);
    for (int i = beg + threadIdx.x; i < end; i += 256) {
        int d = dst[i];
        int pos = atomicAdd(&cur[d >> SH], 1);     // LDS atomic
        part[pos] = (src[i] << SH) | (d & (BUCK - 1));
    }
}

// per bucket: per-node hist -> scan -> scatter src into dst-sorted part2;
// also rowstart (absolute), dinv, xw = dinv*x
__global__ void __launch_bounds__(512) k_prep(
        const int* __restrict__ part, const int* __restrict__ rs2,
        const int* __restrict__ bse, const float* __restrict__ x,
        int* __restrict__ part2, int* __restrict__ rowstart,
        float* __restrict__ dinv, float2* __restrict__ xw,
        int n, int nbuk, int E) {
    __shared__ int hist[BUCK];
    __shared__ int s[BUCK];
    __shared__ int cur[BUCK];
    int t = threadIdx.x, b = blockIdx.x;
    hist[t] = 0;
    __syncthreads();
    int beg = scan_off(rs2, bse, b * NBLK);
    int end = (b + 1 < nbuk) ? scan_off(rs2, bse, (b + 1) * NBLK) : E;
    for (int i = beg + t; i < end; i += 512)
        atomicAdd(&hist[part[i] & (BUCK - 1)], 1);
    __syncthreads();
    s[t] = hist[t];
    __syncthreads();
    for (int d = 1; d < 512; d <<= 1) {
        int v = (t >= d) ? s[t - d] : 0;
        __syncthreads();
        s[t] += v;
        __syncthreads();
    }
    int excl = s[t] - hist[t];
    cur[t] = beg + excl;
    int node = (b << SH) + t;
    rowstart[node] = beg + excl;
    if (node < n) {
        float di = rsqrtf((float)hist[t] + 1.0f);
        dinv[node] = di;
        float2 xs = *reinterpret_cast<const float2*>(&x[2 * node]);
        xw[node] = make_float2(di * xs.x, di * xs.y);
    }
    __syncthreads();
    for (int i = beg + t; i < end; i += 512) {
        int e = part[i];
        int p = atomicAdd(&cur[e & (BUCK - 1)], 1);
        part2[p] = e >> SH;                        // src, in dst-sorted position
    }
}

// layer-1: 4 lanes per node gather + butterfly, MLP split 16 hidden units/lane
__global__ void __launch_bounds__(256) k_bz(
        const int* __restrict__ part2, const int* __restrict__ rowstart,
        const float* __restrict__ dinv, const float2* __restrict__ xw,
        const float* __restrict__ W1, const float* __restrict__ b1,
        const float* __restrict__ W2, float4* __restrict__ zw, int n) {
    __shared__ float sW1[128], sb1[64], sW2[192];
    for (int t = threadIdx.x; t < 128; t += 256) sW1[t] = W1[t];
    for (int t = threadIdx.x; t < 64;  t += 256) sb1[t] = b1[t];
    for (int t = threadIdx.x; t < 192; t += 256) sW2[t] = W2[t];
    __syncthreads();
    int tid = blockIdx.x * 256 + threadIdx.x;
    int i = tid >> 2, lane = tid & 3;
    if (i >= n) return;                            // whole 4-lane group exits together
    int beg = rowstart[i], end = rowstart[i + 1];
    float a0 = 0.f, a1 = 0.f;
    for (int e = beg + lane; e < end; e += 4) {    // lanes 0..3 read contiguous part2
        float2 v = xw[part2[e]];
        a0 += v.x; a1 += v.y;
    }
    if (lane == 0) {                               // self-loop term once
        float2 self = xw[i];
        a0 += self.x; a1 += self.y;
    }
    a0 += __shfl_xor(a0, 1); a0 += __shfl_xor(a0, 2);
    a1 += __shfl_xor(a1, 1); a1 += __shfl_xor(a1, 2);
    float di = dinv[i];
    a0 *= di; a1 *= di;
    float z0 = 0.f, z1 = 0.f, z2 = 0.f;
    int j0 = lane << 4;
#pragma unroll
    for (int jj = 0; jj < 16; ++jj) {
        int j = j0 + jj;
        float h = fmaf(a0, sW1[j], fmaf(a1, sW1[64 + j], sb1[j]));
        h = fmaxf(h, 0.f);
        z0 = fmaf(h, sW2[3 * j],     z0);
        z1 = fmaf(h, sW2[3 * j + 1], z1);
        z2 = fmaf(h, sW2[3 * j + 2], z2);
    }
    z0 += __shfl_xor(z0, 1); z0 += __shfl_xor(z0, 2);
    z1 += __shfl_xor(z1, 1); z1 += __shfl_xor(z1, 2);
    z2 += __shfl_xor(z2, 1); z2 += __shfl_xor(z2, 2);
    if (lane == 0)
        zw[i] = make_float4(di * z0, di * z1, di * z2, 0.f);   // pre-scaled payload
}

// layer-2: 4 lanes per node gather + butterfly; epilogue + sorted-batch wave pooling
__global__ void __launch_bounds__(256) k_bout(
        const int* __restrict__ part2, const int* __restrict__ rowstart,
        const float* __restrict__ dinv, const float4* __restrict__ zw,
        const float* __restrict__ b2, const int* __restrict__ batch,
        float* __restrict__ pooled, float* __restrict__ cnt, int n) {
    int tid = blockIdx.x * 256 + threadIdx.x;
    int i = tid >> 2, lane = tid & 3;
    float o0 = 0.f, o1 = 0.f, o2 = 0.f, vc = 0.f;
    int g = -1;
    if (i < n) {
        int beg = rowstart[i], end = rowstart[i + 1];
        float a0 = 0.f, a1 = 0.f, a2 = 0.f;
        for (int e = beg + lane; e < end; e += 4) {
            float4 v = zw[part2[e]];
            a0 += v.x; a1 += v.y; a2 += v.z;
        }
        if (lane == 0) {
            float4 self = zw[i];
            a0 += self.x; a1 += self.y; a2 += self.z;
        }
        a0 += __shfl_xor(a0, 1); a0 += __shfl_xor(a0, 2);
        a1 += __shfl_xor(a1, 1); a1 += __shfl_xor(a1, 2);
        a2 += __shfl_xor(a2, 1); a2 += __shfl_xor(a2, 2);
        if (lane == 0) {                            // one contribution per node
            float di = dinv[i];
            o0 = fmaf(di, a0, b2[0]);
            o1 = fmaf(di, a1, b2[1]);
            o2 = fmaf(di, a2, b2[2]);
            vc = 1.f;
        }
        g = batch[i];
    }
    int g0 = __shfl(g, 0);
    bool uni = __all(g == g0);
    if (uni) {
        for (int off = 32; off; off >>= 1) {
            o0 += __shfl_down(o0, off);
            o1 += __shfl_down(o1, off);
            o2 += __shfl_down(o2, off);
            vc += __shfl_down(vc, off);
        }
        if ((threadIdx.x & 63) == 0 && g0 >= 0) {
            atomicAdd(&pooled[3 * g0],     o0);
            atomicAdd(&pooled[3 * g0 + 1], o1);
            atomicAdd(&pooled[3 * g0 + 2], o2);
            atomicAdd(&cnt[g0], vc);
        }
    } else if (g >= 0 && lane == 0) {
        atomicAdd(&pooled[3 * g],     o0);
        atomicAdd(&pooled[3 * g + 1], o1);
        atomicAdd(&pooled[3 * g + 2], o2);
        atomicAdd(&cnt[g], 1.f);
    }
}

__global__ void k_out(const float* __restrict__ pooled, const float* __restrict__ cnt,
                      float* __restrict__ out, int G) {
    int g = blockIdx.x * blockDim.x + threadIdx.x;
    if (g >= G) return;
    float c = fmaxf(cnt[g], 1.0f);
    float p0 = pooled[3 * g] / c, p1 = pooled[3 * g + 1] / c, p2 = pooled[3 * g + 2] / c;
    float m = fmaxf(p0, fmaxf(p1, p2));
    float s = expf(p0 - m) + expf(p1 - m) + expf(p2 - m);
    float l = logf(s);
    out[3 * g]     = p0 - m - l;
    out[3 * g + 1] = p1 - m - l;
    out[3 * g + 2] = p2 - m - l;
}

// ============ PATH B: fallback (atomic scatter) ============

__global__ void kB_deg(const int* __restrict__ dst, float* __restrict__ deg, int E) {
    int i = blockIdx.x * blockDim.x + threadIdx.x;
    if (i < E) atomicAdd(&deg[dst[i]], 1.0f);
}

__global__ void kB_dinv(float* __restrict__ deg, int n) {
    int i = blockIdx.x * blockDim.x + threadIdx.x;
    if (i < n) deg[i] = rsqrtf(deg[i] + 1.0f);
}

__global__ void kB_agg1(const int* __restrict__ src, const int* __restrict__ dst,
                        const float* __restrict__ dinv, const float* __restrict__ x,
                        float* __restrict__ agg1, int E) {
    int i = blockIdx.x * blockDim.x + threadIdx.x;
    if (i >= E) return;
    int s = src[i], d = dst[i];
    float w = dinv[s] * dinv[d];
    float2 xs = *reinterpret_cast<const float2*>(&x[2 * s]);
    atomicAdd(&agg1[2 * d],     w * xs.x);
    atomicAdd(&agg1[2 * d + 1], w * xs.y);
}

__global__ void kB_z(const float* __restrict__ agg1, const float* __restrict__ x,
                     const float* __restrict__ dinv,
                     const float* __restrict__ W1, const float* __restrict__ b1,
                     const float* __restrict__ W2, float* __restrict__ z, int n) {
    __shared__ float sW1[128], sb1[64], sW2[192];
    for (int t = threadIdx.x; t < 128; t += blockDim.x) sW1[t] = W1[t];
    for (int t = threadIdx.x; t < 64;  t += blockDim.x) sb1[t] = b1[t];
    for (int t = threadIdx.x; t < 192; t += blockDim.x) sW2[t] = W2[t];
    __syncthreads();
    int i = blockIdx.x * blockDim.x + threadIdx.x;
    if (i >= n) return;
    float di = dinv[i], w = di * di;
    float2 xs = *reinterpret_cast<const float2*>(&x[2 * i]);
    float a0 = agg1[2 * i]     + w * xs.x;
    float a1 = agg1[2 * i + 1] + w * xs.y;
    float z0 = 0.f, z1 = 0.f, z2 = 0.f;
#pragma unroll
    for (int j = 0; j < 64; ++j) {
        float h = fmaf(a0, sW1[j], fmaf(a1, sW1[64 + j], sb1[j]));
        h = fmaxf(h, 0.f);
        z0 = fmaf(h, sW2[3 * j],     z0);
        z1 = fmaf(h, sW2[3 * j + 1], z1);
        z2 = fmaf(h, sW2[3 * j + 2], z2);
    }
    z[3 * i] = z0; z[3 * i + 1] = z1; z[3 * i + 2] = z2;
}

__global__ void kB_agg2(const int* __restrict__ src, const int* __restrict__ dst,
                        const float* __restrict__ dinv, const float* __restrict__ z,
                        float* __restrict__ agg2, int E) {
    int i = blockIdx.x * blockDim.x + threadIdx.x;
    if (i >= E) return;
    int s = src[i], d = dst[i];
    float w = dinv[s] * dinv[d];
    atomicAdd(&agg2[3 * d],     w * z[3 * s]);
    atomicAdd(&agg2[3 * d + 1], w * z[3 * s + 1]);
    atomicAdd(&agg2[3 * d + 2], w * z[3 * s + 2]);
}

__global__ void kB_pool(const float* __restrict__ agg2, const float* __restrict__ z,
                        const float* __restrict__ dinv, const float* __restrict__ b2,
                        const int* __restrict__ batch,
                        float* __restrict__ pooled, float* __restrict__ cnt, int n) {
    int i = blockIdx.x * blockDim.x + threadIdx.x;
    if (i >= n) return;
    float di = dinv[i], w = di * di;
    float o0 = agg2[3 * i]     + w * z[3 * i]     + b2[0];
    float o1 = agg2[3 * i + 1] + w * z[3 * i + 1] + b2[1];
    float o2 = agg2[3 * i + 2] + w * z[3 * i + 2] + b2[2];
    int g = batch[i];
    atomicAdd(&pooled[3 * g],     o0);
    atomicAdd(&pooled[3 * g + 1], o1);
    atomicAdd(&pooled[3 * g + 2], o2);
    atomicAdd(&cnt[g], 1.0f);
}

// ============ launch ============

extern "C" void kernel_launch(void* const* d_in, const int* in_sizes, int n_in,
                              void* d_out, int out_size, void* d_ws, size_t ws_size,
                              hipStream_t stream) {
    const float* x     = (const float*)d_in[0];
    const int*   ei    = (const int*)  d_in[1];
    const int*   batch = (const int*)  d_in[2];
    const float* W1    = (const float*)d_in[3];
    const float* b1    = (const float*)d_in[4];
    const float* W2    = (const float*)d_in[5];
    const float* b2    = (const float*)d_in[6];
    float*       out   = (float*)d_out;

    const int n = in_sizes[2];
    const int E = in_sizes[1] / 2;
    const int G = out_size / 3;
    const int* src = ei;
    const int* dst = ei + E;
    const int B = 256;

    const int nbuk  = (n + BUCK - 1) >> SH;
    const int chunk = (E + NBLK - 1) / NBLK;
    const int M     = nbuk * NBLK;
    const int NB2   = (M + 255) / 256;

    // Path-A workspace layout (4B units)
    size_t o = 0;
    size_t off_h2   = o; o += M;
    size_t off_rs2  = o; o += M;
    size_t off_bs   = o; o += 1024;
    size_t off_bse  = o; o += 1024;
    size_t off_part = o; o += E;
    size_t off_p2   = o; o += E;
    size_t off_row  = o; o += (size_t)nbuk * BUCK + 1;
    size_t off_dinv = o; o += n;
    size_t off_xw   = o; o += (size_t)2 * n;
    o = (o + 3) & ~(size_t)3;                 // 16B-align zw
    size_t off_zw   = o; o += (size_t)4 * n;
    size_t off_pool = o; o += (size_t)3 * G;
    size_t off_cnt  = o; o += G;
    size_t needA = o * 4;

    if (ws_size >= needA && nbuk <= NBUK_MAX && NB2 <= 1024) {
        int*    h2     = (int*)d_ws + off_h2;
        int*    rs2    = (int*)d_ws + off_rs2;
        int*    bs     = (int*)d_ws + off_bs;
        int*    bse    = (int*)d_ws + off_bse;
        int*    part   = (int*)d_ws + off_part;
        int*    part2  = (int*)d_ws + off_p2;
        int*    row    = (int*)d_ws + off_row;
        float*  dinv   = (float*)d_ws + off_dinv;
        float2* xw     = (float2*)((float*)d_ws + off_xw);
        float4* zw     = (float4*)((float*)d_ws + off_zw);
        float*  pooled = (float*)d_ws + off_pool;
        float*  cnt    = (float*)d_ws + off_cnt;

        hipMemsetAsync(pooled, 0, (size_t)4 * G * 4, stream);  // pooled+cnt contiguous
        k_pcount<<<NBLK, 256, 0, stream>>>(dst, h2, E, nbuk, chunk);
        k_scanA <<<NB2, 256, 0, stream>>>(h2, rs2, bs, M);
        k_scanB <<<1, 1024, 0, stream>>>(bs, bse, NB2);
        k_pfill <<<NBLK, 256, 0, stream>>>(src, dst, rs2, bse, part, E, nbuk, chunk);
        k_prep  <<<nbuk, 512, 0, stream>>>(part, rs2, bse, x, part2, row, dinv, xw, n, nbuk, E);
        k_bz    <<<(4 * n + 255) / 256, 256, 0, stream>>>(part2, row, dinv, xw, W1, b1, W2, zw, n);
        k_bout  <<<(4 * n + 255) / 256, 256, 0, stream>>>(part2, row, dinv, zw, b2, batch, pooled, cnt, n);
        k_out   <<<(G + B - 1) / B, B, 0, stream>>>(pooled, cnt, out, G);
    } else {
        float* ws     = (float*)d_ws;
        float* deg    = ws;
        float* agg1   = deg + n;
        float* agg2   = agg1 + 2 * (size_t)n;
        float* pooled = agg2 + 3 * (size_t)n;
        float* cnt    = pooled + 3 * (size_t)G;
        float* zf     = cnt + G;

        size_t zero_floats = (size_t)6 * n + (size_t)4 * G;
        hipMemsetAsync(ws, 0, zero_floats * sizeof(float), stream);
        kB_deg <<<(E + B - 1) / B, B, 0, stream>>>(dst, deg, E);
        kB_dinv<<<(n + B - 1) / B, B, 0, stream>>>(deg, n);
        kB_agg1<<<(E + B - 1) / B, B, 0, stream>>>(src, dst, deg, x, agg1, E);
        kB_z   <<<(n + B - 1) / B, B, 0, stream>>>(agg1, x, deg, W1, b1, W2, zf, n);
        kB_agg2<<<(E + B - 1) / B, B, 0, stream>>>(src, dst, deg, zf, agg2, E);
        kB_pool<<<(n + B - 1) / B, B, 0, stream>>>(agg2, zf, deg, b2, batch, pooled, cnt, n);
        k_out  <<<(G + B - 1) / B, B, 0, stream>>>(pooled, cnt, out, G);
    }
}